// Round 1
// baseline (1767.833 us; speedup 1.0000x reference)
//
#include <hip/hip_runtime.h>
#include <math.h>

#define cN0 200000
#define cN1 50000
#define cN2 10000
#define cL  10
#define cE0 800000
#define cE1 160000
#define cV  100000
#define cIN 128
#define cH  256
#define cU  32
#define cLP 128

__device__ __forceinline__ float wave_sum(float v) {
#pragma unroll
    for (int m = 1; m < 64; m <<= 1) v += __shfl_xor(v, m);
    return v;
}

// ---------------- embedding + LN + relu -> e0 (N0 x 128) ----------------
__global__ __launch_bounds__(256) void embed_kernel(
    const int* __restrict__ x, const float* __restrict__ emb,
    const float* __restrict__ g, const float* __restrict__ b,
    float* __restrict__ e0)
{
    int wave = threadIdx.x >> 6, lane = threadIdx.x & 63;
    int n = blockIdx.x * 4 + wave;
    if (n >= cN0) return;
    const int* xr = x + (size_t)n * cL;
    float ax = 0.f, ay = 0.f;
#pragma unroll
    for (int t = 0; t < cL; ++t) {
        int tok = xr[t];
        if (tok != 0) {
            float2 v = *(const float2*)&emb[(size_t)tok * cIN + 2 * lane];
            ax += v.x; ay += v.y;
        }
    }
    float s1 = wave_sum(ax + ay);
    float s2 = wave_sum(ax * ax + ay * ay);
    float mean = s1 * (1.f / cIN);
    float var = s2 * (1.f / cIN) - mean * mean;
    float rstd = rsqrtf(var + 1e-5f);
    float2 gv = *(const float2*)&g[2 * lane];
    float2 bv = *(const float2*)&b[2 * lane];
    float2 o;
    o.x = fmaxf((ax - mean) * rstd * gv.x + bv.x, 0.f);
    o.y = fmaxf((ay - mean) * rstd * gv.y + bv.y, 0.f);
    *(float2*)&e0[(size_t)n * cIN + 2 * lane] = o;
}

// ---------------- CSR build ----------------
__global__ void count_kernel(const int* __restrict__ dst, int E, int* __restrict__ cnt)
{
    int e = blockIdx.x * 256 + threadIdx.x;
    if (e < E) atomicAdd(&cnt[dst[e]], 1);
}

__global__ __launch_bounds__(1024) void scan_kernel(const int* __restrict__ cnt,
                                                    int* __restrict__ off, int n)
{
    __shared__ int ps[1024];
    int t = threadIdx.x;
    int chunk = (n + 1023) / 1024;
    int lo = t * chunk;
    int hi = min(lo + chunk, n);
    int s = 0;
    for (int i = lo; i < hi; ++i) s += cnt[i];
    ps[t] = s;
    __syncthreads();
    for (int d = 1; d < 1024; d <<= 1) {
        int v = (t >= d) ? ps[t - d] : 0;
        __syncthreads();
        ps[t] += v;
        __syncthreads();
    }
    int run = ps[t] - s;  // exclusive prefix
    for (int i = lo; i < hi; ++i) { off[i] = run; run += cnt[i]; }
    if (hi == n) off[n] = run;
}

__global__ void scatter_kernel(const int* __restrict__ dst, int E,
                               const int* __restrict__ off, int* __restrict__ pos,
                               int* __restrict__ eid)
{
    int e = blockIdx.x * 256 + threadIdx.x;
    if (e < E) {
        int d = dst[e];
        int p = atomicAdd(&pos[d], 1);
        eid[off[d] + p] = e;
    }
}

// ---------------- edge MLP: A = sigmoid(w2 . relu(LN(f@w1.T + b1)) + b2) ----------------
// f = [|ui-uj|, ui+uj, ui*uj]  (96), ui = uni[dst[e]*stride_i], uj = unj[src[e]*stride_j]
__global__ __launch_bounds__(256) void edge_mlp_kernel(
    const float* __restrict__ uni, int stride_i,
    const float* __restrict__ unj, int stride_j,
    const int* __restrict__ src, const int* __restrict__ dst, int E,
    const float* __restrict__ w1, const float* __restrict__ b1v,
    const float* __restrict__ gv, const float* __restrict__ bnv,
    const float* __restrict__ w2, const float* __restrict__ b2,
    float* __restrict__ A)
{
    __shared__ float Wt[96 * 128];     // Wt[k][o]
    __shared__ float par[4 * 128];     // b1 | g | bn | w2
    __shared__ float4 fbuf[4][96];     // per wave: f[k] for 4 edge slots
    int tid = threadIdx.x;
    for (int i = tid; i < 96 * 128; i += 256) {
        int o = i / 96, k = i - o * 96;
        Wt[k * 128 + o] = w1[i];
    }
    if (tid < 128) {
        par[tid] = b1v[tid];
        par[128 + tid] = gv[tid];
        par[256 + tid] = bnv[tid];
        par[384 + tid] = w2[tid];
    }
    __syncthreads();
    int wave = tid >> 6, lane = tid & 63;
    float b2s = b2[0];
    int o0 = 2 * lane;
    float2 b1p = *(const float2*)&par[o0];
    float2 gp  = *(const float2*)&par[128 + o0];
    float2 bnp = *(const float2*)&par[256 + o0];
    float2 w2p = *(const float2*)&par[384 + o0];

    int perIter = gridDim.x * 16;
    int nIter = (E + perIter - 1) / perIter;
    for (int it = 0; it < nIter; ++it) {
        int ebase = (it * gridDim.x + blockIdx.x) * 16 + wave * 4;
        if (lane < 32) {
#pragma unroll
            for (int s = 0; s < 4; ++s) {
                int e = ebase + s;
                float fa = 0.f, fs = 0.f, fp = 0.f;
                if (e < E) {
                    float ui = uni[(size_t)dst[e] * stride_i + lane];
                    float uj = unj[(size_t)src[e] * stride_j + lane];
                    fa = fabsf(ui - uj); fs = ui + uj; fp = ui * uj;
                }
                ((float*)&fbuf[wave][lane])[s] = fa;
                ((float*)&fbuf[wave][32 + lane])[s] = fs;
                ((float*)&fbuf[wave][64 + lane])[s] = fp;
            }
        }
        __syncthreads();
        float accA[4] = {0.f, 0.f, 0.f, 0.f};
        float accB[4] = {0.f, 0.f, 0.f, 0.f};
#pragma unroll 4
        for (int k = 0; k < 96; ++k) {
            float4 f = fbuf[wave][k];
            float2 w = *(const float2*)&Wt[k * 128 + o0];
            accA[0] += f.x * w.x; accB[0] += f.x * w.y;
            accA[1] += f.y * w.x; accB[1] += f.y * w.y;
            accA[2] += f.z * w.x; accB[2] += f.z * w.y;
            accA[3] += f.w * w.x; accB[3] += f.w * w.y;
        }
        __syncthreads();
#pragma unroll
        for (int s = 0; s < 4; ++s) {
            float a0 = accA[s] + b1p.x;
            float a1 = accB[s] + b1p.y;
            float s1 = wave_sum(a0 + a1);
            float s2 = wave_sum(a0 * a0 + a1 * a1);
            float mean = s1 * (1.f / 128.f);
            float var = s2 * (1.f / 128.f) - mean * mean;
            float rstd = rsqrtf(var + 1e-5f);
            float y0 = fmaxf((a0 - mean) * rstd * gp.x + bnp.x, 0.f);
            float y1 = fmaxf((a1 - mean) * rstd * gp.y + bnp.y, 0.f);
            float p = wave_sum(y0 * w2p.x + y1 * w2p.y);
            int e = ebase + s;
            if (lane == 0 && e < E) A[e] = 1.f / (1.f + expf(-(p + b2s)));
        }
    }
}

// ---------------- conv0 aggregation: aggn (N1x128 normalized), h1 un part ----------------
__global__ __launch_bounds__(256) void agg0_kernel(
    const int* __restrict__ off, const int* __restrict__ eid,
    const int* __restrict__ src, const float* __restrict__ A,
    const float* __restrict__ e0, const float* __restrict__ xu,
    float* __restrict__ aggn, float* __restrict__ h1)
{
    int wave = threadIdx.x >> 6, lane = threadIdx.x & 63;
    int i = blockIdx.x * 4 + wave;
    if (i >= cN1) return;
    int s0 = off[i], s1 = off[i + 1];
    float ax = 0.f, ay = 0.f, az = 0.f, aw = 0.f, accA = 0.f;
    for (int idx = s0; idx < s1; ++idx) {
        int e = eid[idx];
        float a = A[e];
        int s = src[e];
        accA += a;
        if (lane < 32) {
            float4 v = *(const float4*)&e0[(size_t)s * cIN + 4 * lane];
            ax += a * v.x; ay += a * v.y; az += a * v.z; aw += a * v.w;
        } else if (lane < 40) {
            float4 v = *(const float4*)&xu[(size_t)s * cU + 4 * (lane - 32)];
            ax += v.x; ay += v.y; az += v.z; aw += v.w;
        }
    }
    float r = (accA > 0.f) ? (1.f / accA) : 0.f;
    if (lane < 32) {
        float4 o = {ax * r, ay * r, az * r, aw * r};
        *(float4*)&aggn[(size_t)i * cIN + 4 * lane] = o;
    } else if (lane < 40) {
        float4 o = {ax, ay, az, aw};
        *(float4*)&h1[(size_t)i * 288 + 256 + 4 * (lane - 32)] = o;
    }
}

// ---------------- build Wt0[k][o]: k<128 -> ll_w0[o][k], else lr_w0[o][k-128] ----------------
__global__ void wtrans_kernel(const float* __restrict__ llw0,
                              const float* __restrict__ lrw0, float* __restrict__ Wt)
{
    int idx = blockIdx.x * 256 + threadIdx.x;
    int k = idx >> 8, o = idx & 255;
    Wt[idx] = (k < 128) ? llw0[o * 128 + k] : lrw0[o * 128 + (k - 128)];
}

// ---------------- linear0: h1[:, :256] = relu([aggn|e0] @ Wt0 + bias) ----------------
__global__ __launch_bounds__(256) void linear0_kernel(
    const float* __restrict__ Aagg, const float* __restrict__ Etgt,
    const float* __restrict__ Wt, const float* __restrict__ bias,
    float* __restrict__ out, int M)
{
    __shared__ float Ta[32 * 68];
    __shared__ float Tb[32 * 68];
    int tid = threadIdx.x;
    int m0 = blockIdx.x * 64;
    int n0 = blockIdx.y * 64;
    int rg = tid >> 4, cg = tid & 15;
    float acc[4][4] = {};
    for (int ck = 0; ck < 8; ++ck) {
        int k0 = ck * 32;
        const float* Asrc = (ck < 4) ? Aagg : Etgt;
        int kc = (ck < 4) ? k0 : (k0 - 128);
        int idx = tid;
#pragma unroll
        for (int rep = 0; rep < 2; ++rep, idx += 256) {
            int r = idx >> 3, kq = (idx & 7) * 4;
            int row = m0 + r;
            float4 v = {0.f, 0.f, 0.f, 0.f};
            if (row < M) v = *(const float4*)&Asrc[(size_t)row * 128 + kc + kq];
            Ta[(kq + 0) * 68 + r] = v.x;
            Ta[(kq + 1) * 68 + r] = v.y;
            Ta[(kq + 2) * 68 + r] = v.z;
            Ta[(kq + 3) * 68 + r] = v.w;
        }
        idx = tid;
#pragma unroll
        for (int rep = 0; rep < 2; ++rep, idx += 256) {
            int k = idx >> 4, nq = (idx & 15) * 4;
            float4 v = *(const float4*)&Wt[(size_t)(k0 + k) * 256 + n0 + nq];
            *(float4*)&Tb[k * 68 + nq] = v;
        }
        __syncthreads();
#pragma unroll
        for (int k = 0; k < 32; ++k) {
            float4 a = *(const float4*)&Ta[k * 68 + 4 * rg];
            float4 b = *(const float4*)&Tb[k * 68 + 4 * cg];
            acc[0][0] += a.x * b.x; acc[0][1] += a.x * b.y; acc[0][2] += a.x * b.z; acc[0][3] += a.x * b.w;
            acc[1][0] += a.y * b.x; acc[1][1] += a.y * b.y; acc[1][2] += a.y * b.z; acc[1][3] += a.y * b.w;
            acc[2][0] += a.z * b.x; acc[2][1] += a.z * b.y; acc[2][2] += a.z * b.z; acc[2][3] += a.z * b.w;
            acc[3][0] += a.w * b.x; acc[3][1] += a.w * b.y; acc[3][2] += a.w * b.z; acc[3][3] += a.w * b.w;
        }
        __syncthreads();
    }
    float4 bv = *(const float4*)&bias[n0 + 4 * cg];
#pragma unroll
    for (int i = 0; i < 4; ++i) {
        int row = m0 + 4 * rg + i;
        if (row < M) {
            float4 o;
            o.x = fmaxf(acc[i][0] + bv.x, 0.f);
            o.y = fmaxf(acc[i][1] + bv.y, 0.f);
            o.z = fmaxf(acc[i][2] + bv.z, 0.f);
            o.w = fmaxf(acc[i][3] + bv.w, 0.f);
            *(float4*)&out[(size_t)row * 288 + n0 + 4 * cg] = o;
        }
    }
}

// ---------------- precompute v1 = out_w@ll_w1, v2 = out_w@lr_w1, c = out_w.ll_b1 + out_b ----------------
__global__ __launch_bounds__(256) void precompute_kernel(
    const float* __restrict__ ow, const float* __restrict__ llw1,
    const float* __restrict__ lrw1, const float* __restrict__ llb1,
    const float* __restrict__ ob,
    float* __restrict__ v1, float* __restrict__ v2, float* __restrict__ cbuf)
{
    __shared__ float w[256];
    __shared__ float red[256];
    int t = threadIdx.x;
    w[t] = ow[t];
    __syncthreads();
    float s1 = 0.f, s2 = 0.f;
    for (int o = 0; o < 256; ++o) {
        float wo = w[o];
        s1 += wo * llw1[o * 256 + t];
        s2 += wo * lrw1[o * 256 + t];
    }
    v1[t] = s1;
    v2[t] = s2;
    red[t] = w[t] * llb1[t];
    __syncthreads();
    for (int d = 128; d > 0; d >>= 1) {
        if (t < d) red[t] += red[t + d];
        __syncthreads();
    }
    if (t == 0) cbuf[0] = red[0] + ob[0];
}

// ---------------- conv1 aggregation fused with final projection ----------------
__global__ __launch_bounds__(256) void agg1_final_kernel(
    const int* __restrict__ off, const int* __restrict__ eid,
    const int* __restrict__ src, const float* __restrict__ A,
    const float* __restrict__ h1, const float* __restrict__ v1,
    const float* __restrict__ v2, const float* __restrict__ cbuf,
    float* __restrict__ out)
{
    int wave = threadIdx.x >> 6, lane = threadIdx.x & 63;
    int n = blockIdx.x * 4 + wave;
    if (n >= cN2) return;
    int s0 = off[n], s1 = off[n + 1];
    float ax = 0.f, ay = 0.f, az = 0.f, aw = 0.f, accA = 0.f;
    for (int idx = s0; idx < s1; ++idx) {
        int e = eid[idx];
        float a = A[e];
        int s = src[e];
        float4 v = *(const float4*)&h1[(size_t)s * 288 + 4 * lane];
        ax += a * v.x; ay += a * v.y; az += a * v.z; aw += a * v.w;
        accA += a;
    }
    float r = (accA > 0.f) ? (1.f / accA) : 0.f;
    float4 t4 = *(const float4*)&h1[(size_t)n * 288 + 4 * lane];
    float4 w1v = *(const float4*)&v1[4 * lane];
    float4 w2v = *(const float4*)&v2[4 * lane];
    float p = r * (ax * w1v.x + ay * w1v.y + az * w1v.z + aw * w1v.w)
            + t4.x * w2v.x + t4.y * w2v.y + t4.z * w2v.z + t4.w * w2v.w;
    p = wave_sum(p);
    if (lane == 0) out[n] = p + cbuf[0];
}

extern "C" void kernel_launch(void* const* d_in, const int* in_sizes, int n_in,
                              void* d_out, int out_size, void* d_ws, size_t ws_size,
                              hipStream_t stream)
{
    const int*   x     = (const int*)d_in[0];
    const float* xu    = (const float*)d_in[1];
    const int*   src0  = (const int*)d_in[2];
    const int*   dst0  = (const int*)d_in[3];
    const int*   src1  = (const int*)d_in[4];
    const int*   dst1  = (const int*)d_in[5];
    const float* emb   = (const float*)d_in[6];
    const float* ln_g  = (const float*)d_in[7];
    const float* ln_b  = (const float*)d_in[8];
    const float* lp_w1 = (const float*)d_in[9];
    const float* lp_b1 = (const float*)d_in[10];
    const float* lp_g  = (const float*)d_in[11];
    const float* lp_bn = (const float*)d_in[12];
    const float* lp_w2 = (const float*)d_in[13];
    const float* lp_b2 = (const float*)d_in[14];
    const float* ll_w0 = (const float*)d_in[15];
    const float* ll_b0 = (const float*)d_in[16];
    const float* lr_w0 = (const float*)d_in[17];
    const float* ll_w1 = (const float*)d_in[18];
    const float* ll_b1 = (const float*)d_in[19];
    const float* lr_w1 = (const float*)d_in[20];
    const float* out_w = (const float*)d_in[21];
    const float* out_b = (const float*)d_in[22];
    float* out = (float*)d_out;

    char* ws = (char*)d_ws;
    size_t off = 0;
    auto alloc = [&](size_t bytes) -> void* {
        void* p = ws + off;
        off = (off + bytes + 255) & ~(size_t)255;
        return p;
    };
    float* e0    = (float*)alloc((size_t)cN0 * cIN * 4);   // 102.4 MB
    float* aggn  = (float*)alloc((size_t)cN1 * cIN * 4);   // 25.6 MB
    float* h1    = (float*)alloc((size_t)cN1 * 288 * 4);   // 57.6 MB
    float* A0    = (float*)alloc((size_t)cE0 * 4);
    float* A1    = (float*)alloc((size_t)cE1 * 4);
    float* Wt0   = (float*)alloc((size_t)256 * 256 * 4);
    float* v1    = (float*)alloc(256 * 4);
    float* v2    = (float*)alloc(256 * 4);
    float* cbuf  = (float*)alloc(64);
    int* cnt0    = (int*)alloc((size_t)cN1 * 4);
    int* off0    = (int*)alloc((size_t)(cN1 + 1) * 4);
    int* pos0    = (int*)alloc((size_t)cN1 * 4);
    int* eid0    = (int*)alloc((size_t)cE0 * 4);
    int* cnt1    = (int*)alloc((size_t)cN2 * 4);
    int* off1    = (int*)alloc((size_t)(cN2 + 1) * 4);
    int* pos1    = (int*)alloc((size_t)cN2 * 4);
    int* eid1    = (int*)alloc((size_t)cE1 * 4);

    hipMemsetAsync(cnt0, 0, (size_t)cN1 * 4, stream);
    hipMemsetAsync(pos0, 0, (size_t)cN1 * 4, stream);
    hipMemsetAsync(cnt1, 0, (size_t)cN2 * 4, stream);
    hipMemsetAsync(pos1, 0, (size_t)cN2 * 4, stream);

    embed_kernel<<<cN0 / 4, 256, 0, stream>>>(x, emb, ln_g, ln_b, e0);

    count_kernel<<<(cE0 + 255) / 256, 256, 0, stream>>>(dst0, cE0, cnt0);
    scan_kernel<<<1, 1024, 0, stream>>>(cnt0, off0, cN1);
    scatter_kernel<<<(cE0 + 255) / 256, 256, 0, stream>>>(dst0, cE0, off0, pos0, eid0);

    edge_mlp_kernel<<<1024, 256, 0, stream>>>(xu, cU, xu, cU, src0, dst0, cE0,
                                              lp_w1, lp_b1, lp_g, lp_bn, lp_w2, lp_b2, A0);

    agg0_kernel<<<(cN1 + 3) / 4, 256, 0, stream>>>(off0, eid0, src0, A0, e0, xu, aggn, h1);

    wtrans_kernel<<<256, 256, 0, stream>>>(ll_w0, lr_w0, Wt0);
    linear0_kernel<<<dim3((cN1 + 63) / 64, 4), 256, 0, stream>>>(aggn, e0, Wt0, ll_b0, h1, cN1);

    count_kernel<<<(cE1 + 255) / 256, 256, 0, stream>>>(dst1, cE1, cnt1);
    scan_kernel<<<1, 1024, 0, stream>>>(cnt1, off1, cN2);
    scatter_kernel<<<(cE1 + 255) / 256, 256, 0, stream>>>(dst1, cE1, off1, pos1, eid1);

    edge_mlp_kernel<<<512, 256, 0, stream>>>(h1 + 256, 288, h1 + 256, 288, src1, dst1, cE1,
                                             lp_w1, lp_b1, lp_g, lp_bn, lp_w2, lp_b2, A1);

    precompute_kernel<<<1, 256, 0, stream>>>(out_w, ll_w1, lr_w1, ll_b1, out_b, v1, v2, cbuf);

    agg1_final_kernel<<<(cN2 + 3) / 4, 256, 0, stream>>>(off1, eid1, src1, A1, h1, v1, v2, cbuf, out);
}

// Round 2
// 1028.523 us; speedup vs baseline: 1.7188x; 1.7188x over previous
//
#include <hip/hip_runtime.h>
#include <math.h>

#define cN0 200000
#define cN1 50000
#define cN2 10000
#define cL  10
#define cE0 800000
#define cE1 160000
#define cV  100000
#define cIN 128
#define cH  256
#define cU  32
#define cLP 128

typedef __attribute__((ext_vector_type(8))) short short8;
typedef __attribute__((ext_vector_type(4))) float floatx4;

__device__ __forceinline__ float wave_sum(float v) {
#pragma unroll
    for (int m = 1; m < 64; m <<= 1) v += __shfl_xor(v, m);
    return v;
}

__device__ __forceinline__ float red16(float v) {
    v += __shfl_xor(v, 1); v += __shfl_xor(v, 2);
    v += __shfl_xor(v, 4); v += __shfl_xor(v, 8);
    return v;
}

__device__ __forceinline__ short bf16_rne(float f) {
    union { float f; unsigned u; } c; c.f = f;
    unsigned r = (c.u + 0x7FFFu + ((c.u >> 16) & 1u)) >> 16;
    return (short)r;
}

// ---------------- embedding + LN + relu -> e0 (N0 x 128) ----------------
__global__ __launch_bounds__(256) void embed_kernel(
    const int* __restrict__ x, const float* __restrict__ emb,
    const float* __restrict__ g, const float* __restrict__ b,
    float* __restrict__ e0)
{
    int wave = threadIdx.x >> 6, lane = threadIdx.x & 63;
    int n = blockIdx.x * 4 + wave;
    if (n >= cN0) return;
    const int* xr = x + (size_t)n * cL;
    float ax = 0.f, ay = 0.f;
#pragma unroll
    for (int t = 0; t < cL; ++t) {
        int tok = xr[t];
        if (tok != 0) {
            float2 v = *(const float2*)&emb[(size_t)tok * cIN + 2 * lane];
            ax += v.x; ay += v.y;
        }
    }
    float s1 = wave_sum(ax + ay);
    float s2 = wave_sum(ax * ax + ay * ay);
    float mean = s1 * (1.f / cIN);
    float var = s2 * (1.f / cIN) - mean * mean;
    float rstd = rsqrtf(var + 1e-5f);
    float2 gv = *(const float2*)&g[2 * lane];
    float2 bv = *(const float2*)&b[2 * lane];
    float2 o;
    o.x = fmaxf((ax - mean) * rstd * gv.x + bv.x, 0.f);
    o.y = fmaxf((ay - mean) * rstd * gv.y + bv.y, 0.f);
    *(float2*)&e0[(size_t)n * cIN + 2 * lane] = o;
}

// ---------------- CSR build ----------------
__global__ void count_kernel(const int* __restrict__ dst, int E, int* __restrict__ cnt)
{
    int e = blockIdx.x * 256 + threadIdx.x;
    if (e < E) atomicAdd(&cnt[dst[e]], 1);
}

__global__ __launch_bounds__(1024) void scan_kernel(const int* __restrict__ cnt,
                                                    int* __restrict__ off, int n)
{
    __shared__ int ps[1024];
    int t = threadIdx.x;
    int chunk = (n + 1023) / 1024;
    int lo = t * chunk;
    int hi = min(lo + chunk, n);
    int s = 0;
    for (int i = lo; i < hi; ++i) s += cnt[i];
    ps[t] = s;
    __syncthreads();
    for (int d = 1; d < 1024; d <<= 1) {
        int v = (t >= d) ? ps[t - d] : 0;
        __syncthreads();
        ps[t] += v;
        __syncthreads();
    }
    int run = ps[t] - s;  // exclusive prefix
    for (int i = lo; i < hi; ++i) { off[i] = run; run += cnt[i]; }
    if (hi == n) off[n] = run;
}

__global__ void scatter_kernel(const int* __restrict__ dst, int E,
                               const int* __restrict__ off, int* __restrict__ pos,
                               int* __restrict__ eid)
{
    int e = blockIdx.x * 256 + threadIdx.x;
    if (e < E) {
        int d = dst[e];
        int p = atomicAdd(&pos[d], 1);
        eid[off[d] + p] = e;
    }
}

// ---------------- edge MLP via MFMA bf16 ----------------
// A_e = sigmoid(w2 . relu(LN(f_e @ w1.T + b1)) + b2),
// f_e = [|ui-uj|, ui+uj, ui*uj] (96).
// Wave handles 16 edges: M=16(edges) x N=128(outs) x K=96 via 8 N-tiles x 3 K-chunks.
__global__ __launch_bounds__(256) void edge_mlp_mfma_kernel(
    const float* __restrict__ uni, int stride_i,
    const float* __restrict__ unj, int stride_j,
    const int* __restrict__ src, const int* __restrict__ dst, int E,
    const float* __restrict__ w1, const float* __restrict__ b1v,
    const float* __restrict__ gv, const float* __restrict__ bnv,
    const float* __restrict__ w2, const float* __restrict__ b2,
    float* __restrict__ A)
{
    __shared__ float par[cLP * 4];  // o -> (b1, g, bn, w2)
    int tid = threadIdx.x;
    if (tid < cLP) {
        par[tid * 4 + 0] = b1v[tid];
        par[tid * 4 + 1] = gv[tid];
        par[tid * 4 + 2] = bnv[tid];
        par[tid * 4 + 3] = w2[tid];
    }
    int lane = tid & 63;
    int n = lane & 15, q = lane >> 4;

    // B fragments (persist in VGPRs): Bf[nt][c][j] = w1[(16nt+n)*96 + 32c + 8q + j]
    short8 Bf[8][3];
#pragma unroll
    for (int nt = 0; nt < 8; ++nt) {
#pragma unroll
        for (int c = 0; c < 3; ++c) {
            const float* p = &w1[(size_t)(16 * nt + n) * 96 + 32 * c + 8 * q];
            float4 v0 = *(const float4*)p;
            float4 v1 = *(const float4*)(p + 4);
            short8 s;
            s[0] = bf16_rne(v0.x); s[1] = bf16_rne(v0.y);
            s[2] = bf16_rne(v0.z); s[3] = bf16_rne(v0.w);
            s[4] = bf16_rne(v1.x); s[5] = bf16_rne(v1.y);
            s[6] = bf16_rne(v1.z); s[7] = bf16_rne(v1.w);
            Bf[nt][c] = s;
        }
    }
    __syncthreads();
    float b2s = b2[0];

    int wid = blockIdx.x * 4 + (tid >> 6);
    int nw = gridDim.x * 4;
    int ngroups = E >> 4;   // E divisible by 16
    for (int g = wid; g < ngroups; g += nw) {
        int ebase = g << 4;
        int e = ebase + n;
        int di = dst[e], si = src[e];
        const float* pi = &uni[(size_t)di * stride_i + 8 * q];
        const float* pj = &unj[(size_t)si * stride_j + 8 * q];
        float4 i0 = *(const float4*)pi, i1 = *(const float4*)(pi + 4);
        float4 j0 = *(const float4*)pj, j1 = *(const float4*)(pj + 4);
        float ui8[8] = {i0.x, i0.y, i0.z, i0.w, i1.x, i1.y, i1.z, i1.w};
        float uj8[8] = {j0.x, j0.y, j0.z, j0.w, j1.x, j1.y, j1.z, j1.w};
        short8 a0, a1, a2;
#pragma unroll
        for (int j = 0; j < 8; ++j) {
            float u = ui8[j], v = uj8[j];
            a0[j] = bf16_rne(fabsf(u - v));
            a1[j] = bf16_rne(u + v);
            a2[j] = bf16_rne(u * v);
        }
        floatx4 acc[8];
#pragma unroll
        for (int nt = 0; nt < 8; ++nt) acc[nt] = (floatx4){0.f, 0.f, 0.f, 0.f};
#pragma unroll
        for (int nt = 0; nt < 8; ++nt) {
            acc[nt] = __builtin_amdgcn_mfma_f32_16x16x32_bf16(a0, Bf[nt][0], acc[nt], 0, 0, 0);
            acc[nt] = __builtin_amdgcn_mfma_f32_16x16x32_bf16(a1, Bf[nt][1], acc[nt], 0, 0, 0);
            acc[nt] = __builtin_amdgcn_mfma_f32_16x16x32_bf16(a2, Bf[nt][2], acc[nt], 0, 0, 0);
        }
        // epilogue: lane holds h[m=4q+r][o=16nt+n] in acc[nt][r]
        float s1[4] = {0.f, 0.f, 0.f, 0.f}, s2[4] = {0.f, 0.f, 0.f, 0.f};
#pragma unroll
        for (int nt = 0; nt < 8; ++nt) {
            float4 pp = *(const float4*)&par[(16 * nt + n) * 4];
#pragma unroll
            for (int r = 0; r < 4; ++r) {
                float h = acc[nt][r] + pp.x;
                acc[nt][r] = h;
                s1[r] += h; s2[r] += h * h;
            }
        }
        float mean[4], rstd[4];
#pragma unroll
        for (int r = 0; r < 4; ++r) {
            s1[r] = red16(s1[r]); s2[r] = red16(s2[r]);
            mean[r] = s1[r] * (1.f / 128.f);
            float var = s2[r] * (1.f / 128.f) - mean[r] * mean[r];
            rstd[r] = rsqrtf(var + 1e-5f);
        }
        float p[4] = {0.f, 0.f, 0.f, 0.f};
#pragma unroll
        for (int nt = 0; nt < 8; ++nt) {
            float4 pp = *(const float4*)&par[(16 * nt + n) * 4];
#pragma unroll
            for (int r = 0; r < 4; ++r) {
                float y = fmaxf((acc[nt][r] - mean[r]) * rstd[r] * pp.y + pp.z, 0.f);
                p[r] += y * pp.w;
            }
        }
#pragma unroll
        for (int r = 0; r < 4; ++r) p[r] = red16(p[r]);
        if (n < 4) {
            float pv = p[n];
            A[ebase + 4 * q + n] = 1.f / (1.f + expf(-(pv + b2s)));
        }
    }
}

// ---------------- conv0 aggregation ----------------
__global__ __launch_bounds__(256) void agg0_kernel(
    const int* __restrict__ off, const int* __restrict__ eid,
    const int* __restrict__ src, const float* __restrict__ A,
    const float* __restrict__ e0, const float* __restrict__ xu,
    float* __restrict__ aggn, float* __restrict__ h1)
{
    int wave = threadIdx.x >> 6, lane = threadIdx.x & 63;
    int i = blockIdx.x * 4 + wave;
    if (i >= cN1) return;
    int s0 = off[i], s1 = off[i + 1];
    float ax = 0.f, ay = 0.f, az = 0.f, aw = 0.f, accA = 0.f;
    for (int idx = s0; idx < s1; ++idx) {
        int e = eid[idx];
        float a = A[e];
        int s = src[e];
        accA += a;
        if (lane < 32) {
            float4 v = *(const float4*)&e0[(size_t)s * cIN + 4 * lane];
            ax += a * v.x; ay += a * v.y; az += a * v.z; aw += a * v.w;
        } else if (lane < 40) {
            float4 v = *(const float4*)&xu[(size_t)s * cU + 4 * (lane - 32)];
            ax += v.x; ay += v.y; az += v.z; aw += v.w;
        }
    }
    float r = (accA > 0.f) ? (1.f / accA) : 0.f;
    if (lane < 32) {
        float4 o = {ax * r, ay * r, az * r, aw * r};
        *(float4*)&aggn[(size_t)i * cIN + 4 * lane] = o;
    } else if (lane < 40) {
        float4 o = {ax, ay, az, aw};
        *(float4*)&h1[(size_t)i * 288 + 256 + 4 * (lane - 32)] = o;
    }
}

// ---------------- build Wt0[k][o] ----------------
__global__ void wtrans_kernel(const float* __restrict__ llw0,
                              const float* __restrict__ lrw0, float* __restrict__ Wt)
{
    int idx = blockIdx.x * 256 + threadIdx.x;
    int k = idx >> 8, o = idx & 255;
    Wt[idx] = (k < 128) ? llw0[o * 128 + k] : lrw0[o * 128 + (k - 128)];
}

// ---------------- linear0 ----------------
__global__ __launch_bounds__(256) void linear0_kernel(
    const float* __restrict__ Aagg, const float* __restrict__ Etgt,
    const float* __restrict__ Wt, const float* __restrict__ bias,
    float* __restrict__ out, int M)
{
    __shared__ float Ta[32 * 68];
    __shared__ float Tb[32 * 68];
    int tid = threadIdx.x;
    int m0 = blockIdx.x * 64;
    int n0 = blockIdx.y * 64;
    int rg = tid >> 4, cg = tid & 15;
    float acc[4][4] = {};
    for (int ck = 0; ck < 8; ++ck) {
        int k0 = ck * 32;
        const float* Asrc = (ck < 4) ? Aagg : Etgt;
        int kc = (ck < 4) ? k0 : (k0 - 128);
        int idx = tid;
#pragma unroll
        for (int rep = 0; rep < 2; ++rep, idx += 256) {
            int r = idx >> 3, kq = (idx & 7) * 4;
            int row = m0 + r;
            float4 v = {0.f, 0.f, 0.f, 0.f};
            if (row < M) v = *(const float4*)&Asrc[(size_t)row * 128 + kc + kq];
            Ta[(kq + 0) * 68 + r] = v.x;
            Ta[(kq + 1) * 68 + r] = v.y;
            Ta[(kq + 2) * 68 + r] = v.z;
            Ta[(kq + 3) * 68 + r] = v.w;
        }
        idx = tid;
#pragma unroll
        for (int rep = 0; rep < 2; ++rep, idx += 256) {
            int k = idx >> 4, nq = (idx & 15) * 4;
            float4 v = *(const float4*)&Wt[(size_t)(k0 + k) * 256 + n0 + nq];
            *(float4*)&Tb[k * 68 + nq] = v;
        }
        __syncthreads();
#pragma unroll
        for (int k = 0; k < 32; ++k) {
            float4 a = *(const float4*)&Ta[k * 68 + 4 * rg];
            float4 b = *(const float4*)&Tb[k * 68 + 4 * cg];
            acc[0][0] += a.x * b.x; acc[0][1] += a.x * b.y; acc[0][2] += a.x * b.z; acc[0][3] += a.x * b.w;
            acc[1][0] += a.y * b.x; acc[1][1] += a.y * b.y; acc[1][2] += a.y * b.z; acc[1][3] += a.y * b.w;
            acc[2][0] += a.z * b.x; acc[2][1] += a.z * b.y; acc[2][2] += a.z * b.z; acc[2][3] += a.z * b.w;
            acc[3][0] += a.w * b.x; acc[3][1] += a.w * b.y; acc[3][2] += a.w * b.z; acc[3][3] += a.w * b.w;
        }
        __syncthreads();
    }
    float4 bv = *(const float4*)&bias[n0 + 4 * cg];
#pragma unroll
    for (int i = 0; i < 4; ++i) {
        int row = m0 + 4 * rg + i;
        if (row < M) {
            float4 o;
            o.x = fmaxf(acc[i][0] + bv.x, 0.f);
            o.y = fmaxf(acc[i][1] + bv.y, 0.f);
            o.z = fmaxf(acc[i][2] + bv.z, 0.f);
            o.w = fmaxf(acc[i][3] + bv.w, 0.f);
            *(float4*)&out[(size_t)row * 288 + n0 + 4 * cg] = o;
        }
    }
}

// ---------------- precompute final projection vectors ----------------
__global__ __launch_bounds__(256) void precompute_kernel(
    const float* __restrict__ ow, const float* __restrict__ llw1,
    const float* __restrict__ lrw1, const float* __restrict__ llb1,
    const float* __restrict__ ob,
    float* __restrict__ v1, float* __restrict__ v2, float* __restrict__ cbuf)
{
    __shared__ float w[256];
    __shared__ float red[256];
    int t = threadIdx.x;
    w[t] = ow[t];
    __syncthreads();
    float s1 = 0.f, s2 = 0.f;
    for (int o = 0; o < 256; ++o) {
        float wo = w[o];
        s1 += wo * llw1[o * 256 + t];
        s2 += wo * lrw1[o * 256 + t];
    }
    v1[t] = s1;
    v2[t] = s2;
    red[t] = w[t] * llb1[t];
    __syncthreads();
    for (int d = 128; d > 0; d >>= 1) {
        if (t < d) red[t] += red[t + d];
        __syncthreads();
    }
    if (t == 0) cbuf[0] = red[0] + ob[0];
}

// ---------------- conv1 aggregation fused with final projection ----------------
__global__ __launch_bounds__(256) void agg1_final_kernel(
    const int* __restrict__ off, const int* __restrict__ eid,
    const int* __restrict__ src, const float* __restrict__ A,
    const float* __restrict__ h1, const float* __restrict__ v1,
    const float* __restrict__ v2, const float* __restrict__ cbuf,
    float* __restrict__ out)
{
    int wave = threadIdx.x >> 6, lane = threadIdx.x & 63;
    int n = blockIdx.x * 4 + wave;
    if (n >= cN2) return;
    int s0 = off[n], s1 = off[n + 1];
    float ax = 0.f, ay = 0.f, az = 0.f, aw = 0.f, accA = 0.f;
    for (int idx = s0; idx < s1; ++idx) {
        int e = eid[idx];
        float a = A[e];
        int s = src[e];
        float4 v = *(const float4*)&h1[(size_t)s * 288 + 4 * lane];
        ax += a * v.x; ay += a * v.y; az += a * v.z; aw += a * v.w;
        accA += a;
    }
    float r = (accA > 0.f) ? (1.f / accA) : 0.f;
    float4 t4 = *(const float4*)&h1[(size_t)n * 288 + 4 * lane];
    float4 w1v = *(const float4*)&v1[4 * lane];
    float4 w2v = *(const float4*)&v2[4 * lane];
    float p = r * (ax * w1v.x + ay * w1v.y + az * w1v.z + aw * w1v.w)
            + t4.x * w2v.x + t4.y * w2v.y + t4.z * w2v.z + t4.w * w2v.w;
    p = wave_sum(p);
    if (lane == 0) out[n] = p + cbuf[0];
}

extern "C" void kernel_launch(void* const* d_in, const int* in_sizes, int n_in,
                              void* d_out, int out_size, void* d_ws, size_t ws_size,
                              hipStream_t stream)
{
    const int*   x     = (const int*)d_in[0];
    const float* xu    = (const float*)d_in[1];
    const int*   src0  = (const int*)d_in[2];
    const int*   dst0  = (const int*)d_in[3];
    const int*   src1  = (const int*)d_in[4];
    const int*   dst1  = (const int*)d_in[5];
    const float* emb   = (const float*)d_in[6];
    const float* ln_g  = (const float*)d_in[7];
    const float* ln_b  = (const float*)d_in[8];
    const float* lp_w1 = (const float*)d_in[9];
    const float* lp_b1 = (const float*)d_in[10];
    const float* lp_g  = (const float*)d_in[11];
    const float* lp_bn = (const float*)d_in[12];
    const float* lp_w2 = (const float*)d_in[13];
    const float* lp_b2 = (const float*)d_in[14];
    const float* ll_w0 = (const float*)d_in[15];
    const float* ll_b0 = (const float*)d_in[16];
    const float* lr_w0 = (const float*)d_in[17];
    const float* ll_w1 = (const float*)d_in[18];
    const float* ll_b1 = (const float*)d_in[19];
    const float* lr_w1 = (const float*)d_in[20];
    const float* out_w = (const float*)d_in[21];
    const float* out_b = (const float*)d_in[22];
    float* out = (float*)d_out;

    char* ws = (char*)d_ws;
    size_t off = 0;
    auto alloc = [&](size_t bytes) -> void* {
        void* p = ws + off;
        off = (off + bytes + 255) & ~(size_t)255;
        return p;
    };
    float* e0    = (float*)alloc((size_t)cN0 * cIN * 4);
    float* aggn  = (float*)alloc((size_t)cN1 * cIN * 4);
    float* h1    = (float*)alloc((size_t)cN1 * 288 * 4);
    float* A0    = (float*)alloc((size_t)cE0 * 4);
    float* A1    = (float*)alloc((size_t)cE1 * 4);
    float* Wt0   = (float*)alloc((size_t)256 * 256 * 4);
    float* v1    = (float*)alloc(256 * 4);
    float* v2    = (float*)alloc(256 * 4);
    float* cbuf  = (float*)alloc(64);
    int* cnt0    = (int*)alloc((size_t)cN1 * 4);
    int* off0    = (int*)alloc((size_t)(cN1 + 1) * 4);
    int* pos0    = (int*)alloc((size_t)cN1 * 4);
    int* eid0    = (int*)alloc((size_t)cE0 * 4);
    int* cnt1    = (int*)alloc((size_t)cN2 * 4);
    int* off1    = (int*)alloc((size_t)(cN2 + 1) * 4);
    int* pos1    = (int*)alloc((size_t)cN2 * 4);
    int* eid1    = (int*)alloc((size_t)cE1 * 4);

    hipMemsetAsync(cnt0, 0, (size_t)cN1 * 4, stream);
    hipMemsetAsync(pos0, 0, (size_t)cN1 * 4, stream);
    hipMemsetAsync(cnt1, 0, (size_t)cN2 * 4, stream);
    hipMemsetAsync(pos1, 0, (size_t)cN2 * 4, stream);

    embed_kernel<<<cN0 / 4, 256, 0, stream>>>(x, emb, ln_g, ln_b, e0);

    count_kernel<<<(cE0 + 255) / 256, 256, 0, stream>>>(dst0, cE0, cnt0);
    scan_kernel<<<1, 1024, 0, stream>>>(cnt0, off0, cN1);
    scatter_kernel<<<(cE0 + 255) / 256, 256, 0, stream>>>(dst0, cE0, off0, pos0, eid0);

    edge_mlp_mfma_kernel<<<1024, 256, 0, stream>>>(xu, cU, xu, cU, src0, dst0, cE0,
                                                   lp_w1, lp_b1, lp_g, lp_bn, lp_w2, lp_b2, A0);

    agg0_kernel<<<(cN1 + 3) / 4, 256, 0, stream>>>(off0, eid0, src0, A0, e0, xu, aggn, h1);

    wtrans_kernel<<<256, 256, 0, stream>>>(ll_w0, lr_w0, Wt0);
    linear0_kernel<<<dim3((cN1 + 63) / 64, 4), 256, 0, stream>>>(aggn, e0, Wt0, ll_b0, h1, cN1);

    count_kernel<<<(cE1 + 255) / 256, 256, 0, stream>>>(dst1, cE1, cnt1);
    scan_kernel<<<1, 1024, 0, stream>>>(cnt1, off1, cN2);
    scatter_kernel<<<(cE1 + 255) / 256, 256, 0, stream>>>(dst1, cE1, off1, pos1, eid1);

    edge_mlp_mfma_kernel<<<512, 256, 0, stream>>>(h1 + 256, 288, h1 + 256, 288, src1, dst1, cE1,
                                                  lp_w1, lp_b1, lp_g, lp_bn, lp_w2, lp_b2, A1);

    precompute_kernel<<<1, 256, 0, stream>>>(out_w, ll_w1, lr_w1, ll_b1, out_b, v1, v2, cbuf);

    agg1_final_kernel<<<(cN2 + 3) / 4, 256, 0, stream>>>(off1, eid1, src1, A1, h1, v1, v2, cbuf, out);
}

// Round 3
// 919.923 us; speedup vs baseline: 1.9217x; 1.1181x over previous
//
#include <hip/hip_runtime.h>
#include <math.h>

#define cN0 200000
#define cN1 50000
#define cN2 10000
#define cL  10
#define cE0 800000
#define cE1 160000
#define cV  100000
#define cIN 128
#define cH  256
#define cU  32
#define cLP 128

typedef __attribute__((ext_vector_type(8))) short short8;
typedef __attribute__((ext_vector_type(4))) float floatx4;

__device__ __forceinline__ float wave_sum(float v) {
#pragma unroll
    for (int m = 1; m < 64; m <<= 1) v += __shfl_xor(v, m);
    return v;
}

__device__ __forceinline__ float red16(float v) {
    v += __shfl_xor(v, 1); v += __shfl_xor(v, 2);
    v += __shfl_xor(v, 4); v += __shfl_xor(v, 8);
    return v;
}

__device__ __forceinline__ unsigned short bf16_rne(float f) {
    union { float f; unsigned u; } c; c.f = f;
    unsigned r = (c.u + 0x7FFFu + ((c.u >> 16) & 1u)) >> 16;
    return (unsigned short)r;
}

__device__ __forceinline__ float b2f(unsigned short u) {
    union { unsigned u; float f; } c; c.u = ((unsigned)u) << 16;
    return c.f;
}

// ---------------- convert emb table to bf16 ----------------
__global__ __launch_bounds__(256) void cvt_emb_kernel(const float* __restrict__ emb,
                                                      ushort* __restrict__ embB)
{
    size_t i = ((size_t)blockIdx.x * 256 + threadIdx.x) * 4;
    float4 v = *(const float4*)&emb[i];
    ushort4 o;
    o.x = bf16_rne(v.x); o.y = bf16_rne(v.y);
    o.z = bf16_rne(v.z); o.w = bf16_rne(v.w);
    *(ushort4*)&embB[i] = o;
}

// ---------------- build Wb[o][k] bf16 (k<128 -> ll_w0, else lr_w0) ----------------
__global__ __launch_bounds__(256) void cvt_w0_kernel(const float* __restrict__ llw0,
                                                     const float* __restrict__ lrw0,
                                                     ushort* __restrict__ Wb)
{
    int idx = blockIdx.x * 256 + threadIdx.x;   // 32768 threads, 2 elems each
    int i = idx * 2;
    int o = i >> 8, k = i & 255;
    float2 v = (k < 128) ? *(const float2*)&llw0[o * 128 + k]
                         : *(const float2*)&lrw0[o * 128 + (k - 128)];
    ushort2 w;
    w.x = bf16_rne(v.x); w.y = bf16_rne(v.y);
    *(ushort2*)&Wb[i] = w;
}

// ---------------- embedding + LN + relu -> e0 bf16 (N0 x 128) ----------------
__global__ __launch_bounds__(256) void embed_kernel(
    const int* __restrict__ x, const ushort* __restrict__ embB,
    const float* __restrict__ g, const float* __restrict__ b,
    ushort* __restrict__ e0)
{
    int wave = threadIdx.x >> 6, lane = threadIdx.x & 63;
    int n = blockIdx.x * 4 + wave;
    if (n >= cN0) return;
    const int* xr = x + (size_t)n * cL;
    float ax = 0.f, ay = 0.f;
#pragma unroll
    for (int t = 0; t < cL; ++t) {
        int tok = xr[t];
        if (tok != 0) {
            ushort2 v = *(const ushort2*)&embB[(size_t)tok * cIN + 2 * lane];
            ax += b2f(v.x); ay += b2f(v.y);
        }
    }
    float s1 = wave_sum(ax + ay);
    float s2 = wave_sum(ax * ax + ay * ay);
    float mean = s1 * (1.f / cIN);
    float var = s2 * (1.f / cIN) - mean * mean;
    float rstd = rsqrtf(var + 1e-5f);
    float2 gv = *(const float2*)&g[2 * lane];
    float2 bv = *(const float2*)&b[2 * lane];
    ushort2 o;
    o.x = bf16_rne(fmaxf((ax - mean) * rstd * gv.x + bv.x, 0.f));
    o.y = bf16_rne(fmaxf((ay - mean) * rstd * gv.y + bv.y, 0.f));
    *(ushort2*)&e0[(size_t)n * cIN + 2 * lane] = o;
}

// ---------------- CSR build ----------------
__global__ void count_kernel(const int* __restrict__ dst, int E, int* __restrict__ cnt)
{
    int e = blockIdx.x * 256 + threadIdx.x;
    if (e < E) atomicAdd(&cnt[dst[e]], 1);
}

__global__ __launch_bounds__(1024) void scan_kernel(const int* __restrict__ cnt,
                                                    int* __restrict__ off, int n)
{
    __shared__ int ps[1024];
    int t = threadIdx.x;
    int chunk = (n + 1023) / 1024;
    int lo = t * chunk;
    int hi = min(lo + chunk, n);
    int s = 0;
    for (int i = lo; i < hi; ++i) s += cnt[i];
    ps[t] = s;
    __syncthreads();
    for (int d = 1; d < 1024; d <<= 1) {
        int v = (t >= d) ? ps[t - d] : 0;
        __syncthreads();
        ps[t] += v;
        __syncthreads();
    }
    int run = ps[t] - s;
    for (int i = lo; i < hi; ++i) { off[i] = run; run += cnt[i]; }
    if (hi == n) off[n] = run;
}

__global__ void scatter_kernel(const int* __restrict__ dst, int E,
                               const int* __restrict__ off, int* __restrict__ pos,
                               int* __restrict__ eid)
{
    int e = blockIdx.x * 256 + threadIdx.x;
    if (e < E) {
        int d = dst[e];
        int p = atomicAdd(&pos[d], 1);
        eid[off[d] + p] = e;
    }
}

// ---------------- edge MLP via MFMA bf16 ----------------
__global__ __launch_bounds__(256) void edge_mlp_mfma_kernel(
    const float* __restrict__ uni, int stride_i,
    const float* __restrict__ unj, int stride_j,
    const int* __restrict__ src, const int* __restrict__ dst, int E,
    const float* __restrict__ w1, const float* __restrict__ b1v,
    const float* __restrict__ gv, const float* __restrict__ bnv,
    const float* __restrict__ w2, const float* __restrict__ b2,
    float* __restrict__ A)
{
    __shared__ float par[cLP * 4];  // o -> (b1, g, bn, w2)
    int tid = threadIdx.x;
    if (tid < cLP) {
        par[tid * 4 + 0] = b1v[tid];
        par[tid * 4 + 1] = gv[tid];
        par[tid * 4 + 2] = bnv[tid];
        par[tid * 4 + 3] = w2[tid];
    }
    int lane = tid & 63;
    int n = lane & 15, q = lane >> 4;

    short8 Bf[8][3];
#pragma unroll
    for (int nt = 0; nt < 8; ++nt) {
#pragma unroll
        for (int c = 0; c < 3; ++c) {
            const float* p = &w1[(size_t)(16 * nt + n) * 96 + 32 * c + 8 * q];
            float4 v0 = *(const float4*)p;
            float4 v1 = *(const float4*)(p + 4);
            short8 s;
            s[0] = bf16_rne(v0.x); s[1] = bf16_rne(v0.y);
            s[2] = bf16_rne(v0.z); s[3] = bf16_rne(v0.w);
            s[4] = bf16_rne(v1.x); s[5] = bf16_rne(v1.y);
            s[6] = bf16_rne(v1.z); s[7] = bf16_rne(v1.w);
            Bf[nt][c] = s;
        }
    }
    __syncthreads();
    float b2s = b2[0];

    int wid = blockIdx.x * 4 + (tid >> 6);
    int nw = gridDim.x * 4;
    int ngroups = E >> 4;
    for (int g = wid; g < ngroups; g += nw) {
        int ebase = g << 4;
        int e = ebase + n;
        int di = dst[e], si = src[e];
        const float* pi = &uni[(size_t)di * stride_i + 8 * q];
        const float* pj = &unj[(size_t)si * stride_j + 8 * q];
        float4 i0 = *(const float4*)pi, i1 = *(const float4*)(pi + 4);
        float4 j0 = *(const float4*)pj, j1 = *(const float4*)(pj + 4);
        float ui8[8] = {i0.x, i0.y, i0.z, i0.w, i1.x, i1.y, i1.z, i1.w};
        float uj8[8] = {j0.x, j0.y, j0.z, j0.w, j1.x, j1.y, j1.z, j1.w};
        short8 a0, a1, a2;
#pragma unroll
        for (int j = 0; j < 8; ++j) {
            float u = ui8[j], v = uj8[j];
            a0[j] = bf16_rne(fabsf(u - v));
            a1[j] = bf16_rne(u + v);
            a2[j] = bf16_rne(u * v);
        }
        floatx4 acc[8];
#pragma unroll
        for (int nt = 0; nt < 8; ++nt) acc[nt] = (floatx4){0.f, 0.f, 0.f, 0.f};
#pragma unroll
        for (int nt = 0; nt < 8; ++nt) {
            acc[nt] = __builtin_amdgcn_mfma_f32_16x16x32_bf16(a0, Bf[nt][0], acc[nt], 0, 0, 0);
            acc[nt] = __builtin_amdgcn_mfma_f32_16x16x32_bf16(a1, Bf[nt][1], acc[nt], 0, 0, 0);
            acc[nt] = __builtin_amdgcn_mfma_f32_16x16x32_bf16(a2, Bf[nt][2], acc[nt], 0, 0, 0);
        }
        float s1[4] = {0.f, 0.f, 0.f, 0.f}, s2[4] = {0.f, 0.f, 0.f, 0.f};
#pragma unroll
        for (int nt = 0; nt < 8; ++nt) {
            float4 pp = *(const float4*)&par[(16 * nt + n) * 4];
#pragma unroll
            for (int r = 0; r < 4; ++r) {
                float h = acc[nt][r] + pp.x;
                acc[nt][r] = h;
                s1[r] += h; s2[r] += h * h;
            }
        }
        float mean[4], rstd[4];
#pragma unroll
        for (int r = 0; r < 4; ++r) {
            s1[r] = red16(s1[r]); s2[r] = red16(s2[r]);
            mean[r] = s1[r] * (1.f / 128.f);
            float var = s2[r] * (1.f / 128.f) - mean[r] * mean[r];
            rstd[r] = rsqrtf(var + 1e-5f);
        }
        float p[4] = {0.f, 0.f, 0.f, 0.f};
#pragma unroll
        for (int nt = 0; nt < 8; ++nt) {
            float4 pp = *(const float4*)&par[(16 * nt + n) * 4];
#pragma unroll
            for (int r = 0; r < 4; ++r) {
                float y = fmaxf((acc[nt][r] - mean[r]) * rstd[r] * pp.y + pp.z, 0.f);
                p[r] += y * pp.w;
            }
        }
#pragma unroll
        for (int r = 0; r < 4; ++r) p[r] = red16(p[r]);
        if (n < 4) {
            float pv = p[n];
            A[ebase + 4 * q + n] = 1.f / (1.f + expf(-(pv + b2s)));
        }
    }
}

// ---------------- conv0 aggregation: aggn bf16, h1 un fp32 ----------------
__global__ __launch_bounds__(256) void agg0_kernel(
    const int* __restrict__ off, const int* __restrict__ eid,
    const int* __restrict__ src, const float* __restrict__ A,
    const ushort* __restrict__ e0, const float* __restrict__ xu,
    ushort* __restrict__ aggn, float* __restrict__ h1)
{
    int wave = threadIdx.x >> 6, lane = threadIdx.x & 63;
    int i = blockIdx.x * 4 + wave;
    if (i >= cN1) return;
    int s0 = off[i], s1 = off[i + 1];
    float ax = 0.f, ay = 0.f, az = 0.f, aw = 0.f, accA = 0.f;
    for (int idx = s0; idx < s1; ++idx) {
        int e = eid[idx];
        float a = A[e];
        int s = src[e];
        accA += a;
        if (lane < 32) {
            ushort4 v = *(const ushort4*)&e0[(size_t)s * cIN + 4 * lane];
            ax += a * b2f(v.x); ay += a * b2f(v.y);
            az += a * b2f(v.z); aw += a * b2f(v.w);
        } else {
            ax += xu[(size_t)s * cU + (lane - 32)];
        }
    }
    if (lane < 32) {
        float r = (accA > 0.f) ? (1.f / accA) : 0.f;
        ushort4 o;
        o.x = bf16_rne(ax * r); o.y = bf16_rne(ay * r);
        o.z = bf16_rne(az * r); o.w = bf16_rne(aw * r);
        *(ushort4*)&aggn[(size_t)i * cIN + 4 * lane] = o;
    } else {
        h1[(size_t)i * 288 + 256 + (lane - 32)] = ax;
    }
}

// ---------------- linear0 via MFMA: h1[:, :256] = relu([aggn|e0] @ Wb.T + b) ----------------
__global__ __launch_bounds__(256) void linear0_mfma_kernel(
    const ushort* __restrict__ aggn, const ushort* __restrict__ e0,
    const ushort* __restrict__ Wb, const float* __restrict__ bias,
    float* __restrict__ h1)
{
    int tid = threadIdx.x;
    int w = tid >> 6, lane = tid & 63;
    int n = lane & 15, q = lane >> 4;
    short8 Bf[4][8];
    float bia[4];
#pragma unroll
    for (int t = 0; t < 4; ++t) {
        int col = 64 * w + 16 * t + n;
        bia[t] = bias[col];
#pragma unroll
        for (int kc = 0; kc < 8; ++kc)
            Bf[t][kc] = *(const short8*)&Wb[(size_t)col * 256 + kc * 32 + 8 * q];
    }
    for (int g = blockIdx.x; g < cN1 / 16; g += gridDim.x) {
        int m0 = g * 16;
        int row = m0 + n;
        short8 Af[8];
#pragma unroll
        for (int kc = 0; kc < 4; ++kc)
            Af[kc] = *(const short8*)&aggn[(size_t)row * cIN + kc * 32 + 8 * q];
#pragma unroll
        for (int kc = 0; kc < 4; ++kc)
            Af[4 + kc] = *(const short8*)&e0[(size_t)row * cIN + kc * 32 + 8 * q];
#pragma unroll
        for (int t = 0; t < 4; ++t) {
            floatx4 acc = {0.f, 0.f, 0.f, 0.f};
#pragma unroll
            for (int kc = 0; kc < 8; ++kc)
                acc = __builtin_amdgcn_mfma_f32_16x16x32_bf16(Af[kc], Bf[t][kc], acc, 0, 0, 0);
            int col = 64 * w + 16 * t + n;
#pragma unroll
            for (int r = 0; r < 4; ++r) {
                int m = m0 + 4 * q + r;
                h1[(size_t)m * 288 + col] = fmaxf(acc[r] + bia[t], 0.f);
            }
        }
    }
}

// ---------------- precompute final projection vectors ----------------
__global__ __launch_bounds__(256) void precompute_kernel(
    const float* __restrict__ ow, const float* __restrict__ llw1,
    const float* __restrict__ lrw1, const float* __restrict__ llb1,
    const float* __restrict__ ob,
    float* __restrict__ v1, float* __restrict__ v2, float* __restrict__ cbuf)
{
    __shared__ float w[256];
    __shared__ float red[256];
    int t = threadIdx.x;
    w[t] = ow[t];
    __syncthreads();
    float s1 = 0.f, s2 = 0.f;
    for (int o = 0; o < 256; ++o) {
        float wo = w[o];
        s1 += wo * llw1[o * 256 + t];
        s2 += wo * lrw1[o * 256 + t];
    }
    v1[t] = s1;
    v2[t] = s2;
    red[t] = w[t] * llb1[t];
    __syncthreads();
    for (int d = 128; d > 0; d >>= 1) {
        if (t < d) red[t] += red[t + d];
        __syncthreads();
    }
    if (t == 0) cbuf[0] = red[0] + ob[0];
}

// ---------------- conv1 aggregation fused with final projection ----------------
__global__ __launch_bounds__(256) void agg1_final_kernel(
    const int* __restrict__ off, const int* __restrict__ eid,
    const int* __restrict__ src, const float* __restrict__ A,
    const float* __restrict__ h1, const float* __restrict__ v1,
    const float* __restrict__ v2, const float* __restrict__ cbuf,
    float* __restrict__ out)
{
    int wave = threadIdx.x >> 6, lane = threadIdx.x & 63;
    int n = blockIdx.x * 4 + wave;
    if (n >= cN2) return;
    int s0 = off[n], s1 = off[n + 1];
    float ax = 0.f, ay = 0.f, az = 0.f, aw = 0.f, accA = 0.f;
    for (int idx = s0; idx < s1; ++idx) {
        int e = eid[idx];
        float a = A[e];
        int s = src[e];
        float4 v = *(const float4*)&h1[(size_t)s * 288 + 4 * lane];
        ax += a * v.x; ay += a * v.y; az += a * v.z; aw += a * v.w;
        accA += a;
    }
    float r = (accA > 0.f) ? (1.f / accA) : 0.f;
    float4 t4 = *(const float4*)&h1[(size_t)n * 288 + 4 * lane];
    float4 w1v = *(const float4*)&v1[4 * lane];
    float4 w2v = *(const float4*)&v2[4 * lane];
    float p = r * (ax * w1v.x + ay * w1v.y + az * w1v.z + aw * w1v.w)
            + t4.x * w2v.x + t4.y * w2v.y + t4.z * w2v.z + t4.w * w2v.w;
    p = wave_sum(p);
    if (lane == 0) out[n] = p + cbuf[0];
}

extern "C" void kernel_launch(void* const* d_in, const int* in_sizes, int n_in,
                              void* d_out, int out_size, void* d_ws, size_t ws_size,
                              hipStream_t stream)
{
    const int*   x     = (const int*)d_in[0];
    const float* xu    = (const float*)d_in[1];
    const int*   src0  = (const int*)d_in[2];
    const int*   dst0  = (const int*)d_in[3];
    const int*   src1  = (const int*)d_in[4];
    const int*   dst1  = (const int*)d_in[5];
    const float* emb   = (const float*)d_in[6];
    const float* ln_g  = (const float*)d_in[7];
    const float* ln_b  = (const float*)d_in[8];
    const float* lp_w1 = (const float*)d_in[9];
    const float* lp_b1 = (const float*)d_in[10];
    const float* lp_g  = (const float*)d_in[11];
    const float* lp_bn = (const float*)d_in[12];
    const float* lp_w2 = (const float*)d_in[13];
    const float* lp_b2 = (const float*)d_in[14];
    const float* ll_w0 = (const float*)d_in[15];
    const float* ll_b0 = (const float*)d_in[16];
    const float* lr_w0 = (const float*)d_in[17];
    const float* ll_w1 = (const float*)d_in[18];
    const float* ll_b1 = (const float*)d_in[19];
    const float* lr_w1 = (const float*)d_in[20];
    const float* out_w = (const float*)d_in[21];
    const float* out_b = (const float*)d_in[22];
    float* out = (float*)d_out;

    char* ws = (char*)d_ws;
    size_t off = 0;
    auto alloc = [&](size_t bytes) -> void* {
        void* p = ws + off;
        off = (off + bytes + 255) & ~(size_t)255;
        return p;
    };
    ushort* embB = (ushort*)alloc((size_t)cV * cIN * 2);    // 25.6 MB
    ushort* e0   = (ushort*)alloc((size_t)cN0 * cIN * 2);   // 51.2 MB
    ushort* aggn = (ushort*)alloc((size_t)cN1 * cIN * 2);   // 12.8 MB
    float* h1    = (float*)alloc((size_t)cN1 * 288 * 4);    // 57.6 MB
    float* A0    = (float*)alloc((size_t)cE0 * 4);
    float* A1    = (float*)alloc((size_t)cE1 * 4);
    ushort* Wb   = (ushort*)alloc((size_t)256 * 256 * 2);
    float* v1    = (float*)alloc(256 * 4);
    float* v2    = (float*)alloc(256 * 4);
    float* cbuf  = (float*)alloc(64);
    int* cnt0    = (int*)alloc((size_t)cN1 * 4);
    int* off0    = (int*)alloc((size_t)(cN1 + 1) * 4);
    int* pos0    = (int*)alloc((size_t)cN1 * 4);
    int* eid0    = (int*)alloc((size_t)cE0 * 4);
    int* cnt1    = (int*)alloc((size_t)cN2 * 4);
    int* off1    = (int*)alloc((size_t)(cN2 + 1) * 4);
    int* pos1    = (int*)alloc((size_t)cN2 * 4);
    int* eid1    = (int*)alloc((size_t)cE1 * 4);

    hipMemsetAsync(cnt0, 0, (size_t)cN1 * 4, stream);
    hipMemsetAsync(pos0, 0, (size_t)cN1 * 4, stream);
    hipMemsetAsync(cnt1, 0, (size_t)cN2 * 4, stream);
    hipMemsetAsync(pos1, 0, (size_t)cN2 * 4, stream);

    cvt_emb_kernel<<<(cV * cIN) / 1024, 256, 0, stream>>>(emb, embB);
    cvt_w0_kernel<<<128, 256, 0, stream>>>(ll_w0, lr_w0, Wb);

    embed_kernel<<<cN0 / 4, 256, 0, stream>>>(x, embB, ln_g, ln_b, e0);

    count_kernel<<<(cE0 + 255) / 256, 256, 0, stream>>>(dst0, cE0, cnt0);
    scan_kernel<<<1, 1024, 0, stream>>>(cnt0, off0, cN1);
    scatter_kernel<<<(cE0 + 255) / 256, 256, 0, stream>>>(dst0, cE0, off0, pos0, eid0);

    edge_mlp_mfma_kernel<<<1024, 256, 0, stream>>>(xu, cU, xu, cU, src0, dst0, cE0,
                                                   lp_w1, lp_b1, lp_g, lp_bn, lp_w2, lp_b2, A0);

    agg0_kernel<<<(cN1 + 3) / 4, 256, 0, stream>>>(off0, eid0, src0, A0, e0, xu, aggn, h1);

    linear0_mfma_kernel<<<784, 256, 0, stream>>>(aggn, e0, Wb, ll_b0, h1);

    count_kernel<<<(cE1 + 255) / 256, 256, 0, stream>>>(dst1, cE1, cnt1);
    scan_kernel<<<1, 1024, 0, stream>>>(cnt1, off1, cN2);
    scatter_kernel<<<(cE1 + 255) / 256, 256, 0, stream>>>(dst1, cE1, off1, pos1, eid1);

    edge_mlp_mfma_kernel<<<512, 256, 0, stream>>>(h1 + 256, 288, h1 + 256, 288, src1, dst1, cE1,
                                                  lp_w1, lp_b1, lp_g, lp_bn, lp_w2, lp_b2, A1);

    precompute_kernel<<<1, 256, 0, stream>>>(out_w, ll_w1, lr_w1, ll_b1, out_b, v1, v2, cbuf);

    agg1_final_kernel<<<(cN2 + 3) / 4, 256, 0, stream>>>(off1, eid1, src1, A1, h1, v1, v2, cbuf, out);
}

// Round 4
// 768.808 us; speedup vs baseline: 2.2994x; 1.1966x over previous
//
#include <hip/hip_runtime.h>
#include <math.h>

#define cN0 200000
#define cN1 50000
#define cN2 10000
#define cL  10
#define cE0 800000
#define cE1 160000
#define cV  100000
#define cIN 128
#define cH  256
#define cU  32
#define cLP 128

typedef __attribute__((ext_vector_type(8))) short short8;
typedef __attribute__((ext_vector_type(4))) float floatx4;

__device__ __forceinline__ float wave_sum(float v) {
#pragma unroll
    for (int m = 1; m < 64; m <<= 1) v += __shfl_xor(v, m);
    return v;
}

__device__ __forceinline__ float red16(float v) {
    v += __shfl_xor(v, 1); v += __shfl_xor(v, 2);
    v += __shfl_xor(v, 4); v += __shfl_xor(v, 8);
    return v;
}

__device__ __forceinline__ unsigned short bf16_rne(float f) {
    union { float f; unsigned u; } c; c.f = f;
    unsigned r = (c.u + 0x7FFFu + ((c.u >> 16) & 1u)) >> 16;
    return (unsigned short)r;
}

__device__ __forceinline__ float b2f(unsigned short u) {
    union { unsigned u; float f; } c; c.u = ((unsigned)u) << 16;
    return c.f;
}

// ---------------- fp32 -> bf16 converters ----------------
__global__ __launch_bounds__(256) void cvt4_kernel(const float* __restrict__ src,
                                                   ushort* __restrict__ dstp)
{
    size_t i = ((size_t)blockIdx.x * 256 + threadIdx.x) * 4;
    float4 v = *(const float4*)&src[i];
    ushort4 o;
    o.x = bf16_rne(v.x); o.y = bf16_rne(v.y);
    o.z = bf16_rne(v.z); o.w = bf16_rne(v.w);
    *(ushort4*)&dstp[i] = o;
}

// ---------------- build Wb[o][k] bf16 (k<128 -> ll_w0, else lr_w0) ----------------
__global__ __launch_bounds__(256) void cvt_w0_kernel(const float* __restrict__ llw0,
                                                     const float* __restrict__ lrw0,
                                                     ushort* __restrict__ Wb)
{
    int idx = blockIdx.x * 256 + threadIdx.x;
    int i = idx * 2;
    int o = i >> 8, k = i & 255;
    float2 v = (k < 128) ? *(const float2*)&llw0[o * 128 + k]
                         : *(const float2*)&lrw0[o * 128 + (k - 128)];
    ushort2 w;
    w.x = bf16_rne(v.x); w.y = bf16_rne(v.y);
    *(ushort2*)&Wb[i] = w;
}

// ---------------- embedding + LN + relu -> e0 bf16 (branchless, 10-deep ILP) --------
__global__ __launch_bounds__(256) void embed_kernel(
    const int* __restrict__ x, const ushort* __restrict__ embB,
    const float* __restrict__ g, const float* __restrict__ b,
    ushort* __restrict__ e0)
{
    int wave = threadIdx.x >> 6, lane = threadIdx.x & 63;
    int n = blockIdx.x * 4 + wave;
    const int* xr = x + (size_t)n * cL;
    int toks[cL];
#pragma unroll
    for (int t = 0; t < cL; ++t) toks[t] = xr[t];
    unsigned packed[cL];
#pragma unroll
    for (int t = 0; t < cL; ++t)
        packed[t] = *(const unsigned*)&embB[(size_t)toks[t] * cIN + 2 * lane];
    float ax = 0.f, ay = 0.f;
#pragma unroll
    for (int t = 0; t < cL; ++t) {
        unsigned p = (toks[t] != 0) ? packed[t] : 0u;
        union { unsigned u; float f; } lo, hi;
        lo.u = p << 16; hi.u = p & 0xFFFF0000u;
        ax += lo.f; ay += hi.f;
    }
    float s1 = wave_sum(ax + ay);
    float s2 = wave_sum(ax * ax + ay * ay);
    float mean = s1 * (1.f / cIN);
    float var = s2 * (1.f / cIN) - mean * mean;
    float rstd = rsqrtf(var + 1e-5f);
    float2 gv = *(const float2*)&g[2 * lane];
    float2 bv = *(const float2*)&b[2 * lane];
    ushort2 o;
    o.x = bf16_rne(fmaxf((ax - mean) * rstd * gv.x + bv.x, 0.f));
    o.y = bf16_rne(fmaxf((ay - mean) * rstd * gv.y + bv.y, 0.f));
    *(ushort2*)&e0[(size_t)n * cIN + 2 * lane] = o;
}

// ---------------- CSR build ----------------
__global__ void count_kernel(const int* __restrict__ dst, int E, int* __restrict__ cnt)
{
    int e = blockIdx.x * 256 + threadIdx.x;
    if (e < E) atomicAdd(&cnt[dst[e]], 1);
}

__global__ __launch_bounds__(1024) void scan_kernel(const int* __restrict__ cnt,
                                                    int* __restrict__ off, int n)
{
    __shared__ int ps[1024];
    int t = threadIdx.x;
    int chunk = (n + 1023) / 1024;
    int lo = t * chunk;
    int hi = min(lo + chunk, n);
    int s = 0;
    for (int i = lo; i < hi; ++i) s += cnt[i];
    ps[t] = s;
    __syncthreads();
    for (int d = 1; d < 1024; d <<= 1) {
        int v = (t >= d) ? ps[t - d] : 0;
        __syncthreads();
        ps[t] += v;
        __syncthreads();
    }
    int run = ps[t] - s;
    for (int i = lo; i < hi; ++i) { off[i] = run; run += cnt[i]; }
    if (hi == n) off[n] = run;
}

__global__ void scatter_kernel(const int* __restrict__ dst, int E,
                               const int* __restrict__ off, int* __restrict__ pos,
                               int* __restrict__ eid)
{
    int e = blockIdx.x * 256 + threadIdx.x;
    if (e < E) {
        int d = dst[e];
        int p = atomicAdd(&pos[d], 1);
        eid[off[d] + p] = e;
    }
}

// ---------------- edge MLP via MFMA bf16 (u tables in bf16) ----------------
__global__ __launch_bounds__(256) void edge_mlp_mfma_kernel(
    const ushort* __restrict__ uni, int stride_i,
    const ushort* __restrict__ unj, int stride_j,
    const int* __restrict__ src, const int* __restrict__ dst, int E,
    const float* __restrict__ w1, const float* __restrict__ b1v,
    const float* __restrict__ gv, const float* __restrict__ bnv,
    const float* __restrict__ w2, const float* __restrict__ b2,
    float* __restrict__ A)
{
    __shared__ float par[cLP * 4];  // o -> (b1, g, bn, w2)
    int tid = threadIdx.x;
    if (tid < cLP) {
        par[tid * 4 + 0] = b1v[tid];
        par[tid * 4 + 1] = gv[tid];
        par[tid * 4 + 2] = bnv[tid];
        par[tid * 4 + 3] = w2[tid];
    }
    int lane = tid & 63;
    int n = lane & 15, q = lane >> 4;

    short8 Bf[8][3];
#pragma unroll
    for (int nt = 0; nt < 8; ++nt) {
#pragma unroll
        for (int c = 0; c < 3; ++c) {
            const float* p = &w1[(size_t)(16 * nt + n) * 96 + 32 * c + 8 * q];
            float4 v0 = *(const float4*)p;
            float4 v1 = *(const float4*)(p + 4);
            short8 s;
            s[0] = bf16_rne(v0.x); s[1] = bf16_rne(v0.y);
            s[2] = bf16_rne(v0.z); s[3] = bf16_rne(v0.w);
            s[4] = bf16_rne(v1.x); s[5] = bf16_rne(v1.y);
            s[6] = bf16_rne(v1.z); s[7] = bf16_rne(v1.w);
            Bf[nt][c] = s;
        }
    }
    __syncthreads();
    float b2s = b2[0];

    int wid = blockIdx.x * 4 + (tid >> 6);
    int nw = gridDim.x * 4;
    int ngroups = E >> 4;

    int g = wid;
    int di = 0, si = 0;
    if (g < ngroups) {
        int e = (g << 4) + n;
        di = dst[e]; si = src[e];
    }
    while (g < ngroups) {
        // issue current u-row loads
        short8 iv = *(const short8*)&uni[(size_t)di * stride_i + 8 * q];
        short8 jv = *(const short8*)&unj[(size_t)si * stride_j + 8 * q];
        // prefetch next group's indices
        int gn = g + nw;
        if (gn < ngroups) {
            int e2 = (gn << 4) + n;
            di = dst[e2]; si = src[e2];
        }
        short8 a0, a1, a2;
#pragma unroll
        for (int j = 0; j < 8; ++j) {
            float u = b2f((unsigned short)iv[j]);
            float v = b2f((unsigned short)jv[j]);
            a0[j] = bf16_rne(fabsf(u - v));
            a1[j] = bf16_rne(u + v);
            a2[j] = bf16_rne(u * v);
        }
        floatx4 acc[8];
#pragma unroll
        for (int nt = 0; nt < 8; ++nt) acc[nt] = (floatx4){0.f, 0.f, 0.f, 0.f};
#pragma unroll
        for (int nt = 0; nt < 8; ++nt) {
            acc[nt] = __builtin_amdgcn_mfma_f32_16x16x32_bf16(a0, Bf[nt][0], acc[nt], 0, 0, 0);
            acc[nt] = __builtin_amdgcn_mfma_f32_16x16x32_bf16(a1, Bf[nt][1], acc[nt], 0, 0, 0);
            acc[nt] = __builtin_amdgcn_mfma_f32_16x16x32_bf16(a2, Bf[nt][2], acc[nt], 0, 0, 0);
        }
        float s1[4] = {0.f, 0.f, 0.f, 0.f}, s2[4] = {0.f, 0.f, 0.f, 0.f};
#pragma unroll
        for (int nt = 0; nt < 8; ++nt) {
            float4 pp = *(const float4*)&par[(16 * nt + n) * 4];
#pragma unroll
            for (int r = 0; r < 4; ++r) {
                float h = acc[nt][r] + pp.x;
                acc[nt][r] = h;
                s1[r] += h; s2[r] += h * h;
            }
        }
        float mean[4], rstd[4];
#pragma unroll
        for (int r = 0; r < 4; ++r) {
            s1[r] = red16(s1[r]); s2[r] = red16(s2[r]);
            mean[r] = s1[r] * (1.f / 128.f);
            float var = s2[r] * (1.f / 128.f) - mean[r] * mean[r];
            rstd[r] = rsqrtf(var + 1e-5f);
        }
        float p[4] = {0.f, 0.f, 0.f, 0.f};
#pragma unroll
        for (int nt = 0; nt < 8; ++nt) {
            float4 pp = *(const float4*)&par[(16 * nt + n) * 4];
#pragma unroll
            for (int r = 0; r < 4; ++r) {
                float y = fmaxf((acc[nt][r] - mean[r]) * rstd[r] * pp.y + pp.z, 0.f);
                p[r] += y * pp.w;
            }
        }
#pragma unroll
        for (int r = 0; r < 4; ++r) p[r] = red16(p[r]);
        if (n < 4) {
            float pv = p[n];
            A[(g << 4) + 4 * q + n] = 1.f / (1.f + expf(-(pv + b2s)));
        }
        g = gn;
    }
}

// ---------------- conv0 aggregation: aggn bf16, h1b un bf16 ----------------
__global__ __launch_bounds__(256) void agg0_kernel(
    const int* __restrict__ off, const int* __restrict__ eid,
    const int* __restrict__ src, const float* __restrict__ A,
    const ushort* __restrict__ e0, const ushort* __restrict__ xub,
    ushort* __restrict__ aggn, ushort* __restrict__ h1b)
{
    int wave = threadIdx.x >> 6, lane = threadIdx.x & 63;
    int i = blockIdx.x * 4 + wave;
    if (i >= cN1) return;
    int s0 = off[i], s1 = off[i + 1];
    float ax = 0.f, ay = 0.f, az = 0.f, aw = 0.f, accA = 0.f;
    int e = 0, sn = 0; float a = 0.f;
    if (s0 < s1) { e = eid[s0]; a = A[e]; sn = src[e]; }
    for (int idx = s0; idx < s1; ++idx) {
        float ca = a; int cs = sn;
        if (idx + 1 < s1) { int e2 = eid[idx + 1]; a = A[e2]; sn = src[e2]; }
        accA += ca;
        if (lane < 32) {
            ushort4 v = *(const ushort4*)&e0[(size_t)cs * cIN + 4 * lane];
            ax += ca * b2f(v.x); ay += ca * b2f(v.y);
            az += ca * b2f(v.z); aw += ca * b2f(v.w);
        } else {
            ax += b2f(xub[(size_t)cs * cU + (lane - 32)]);
        }
    }
    if (lane < 32) {
        float r = (accA > 0.f) ? (1.f / accA) : 0.f;
        ushort4 o;
        o.x = bf16_rne(ax * r); o.y = bf16_rne(ay * r);
        o.z = bf16_rne(az * r); o.w = bf16_rne(aw * r);
        *(ushort4*)&aggn[(size_t)i * cIN + 4 * lane] = o;
    } else {
        h1b[(size_t)i * 288 + 256 + (lane - 32)] = bf16_rne(ax);
    }
}

// ---------------- linear0 via MFMA: h1b[:, :256] = relu([aggn|e0] @ Wb.T + b) --------
__global__ __launch_bounds__(256) void linear0_mfma_kernel(
    const ushort* __restrict__ aggn, const ushort* __restrict__ e0,
    const ushort* __restrict__ Wb, const float* __restrict__ bias,
    ushort* __restrict__ h1b)
{
    int tid = threadIdx.x;
    int w = tid >> 6, lane = tid & 63;
    int n = lane & 15, q = lane >> 4;
    short8 Bf[4][8];
    float bia[4];
#pragma unroll
    for (int t = 0; t < 4; ++t) {
        int col = 64 * w + 16 * t + n;
        bia[t] = bias[col];
#pragma unroll
        for (int kc = 0; kc < 8; ++kc)
            Bf[t][kc] = *(const short8*)&Wb[(size_t)col * 256 + kc * 32 + 8 * q];
    }
    for (int g = blockIdx.x; g < cN1 / 16; g += gridDim.x) {
        int m0 = g * 16;
        int row = m0 + n;
        short8 Af[8];
#pragma unroll
        for (int kc = 0; kc < 4; ++kc)
            Af[kc] = *(const short8*)&aggn[(size_t)row * cIN + kc * 32 + 8 * q];
#pragma unroll
        for (int kc = 0; kc < 4; ++kc)
            Af[4 + kc] = *(const short8*)&e0[(size_t)row * cIN + kc * 32 + 8 * q];
#pragma unroll
        for (int t = 0; t < 4; ++t) {
            floatx4 acc = {0.f, 0.f, 0.f, 0.f};
#pragma unroll
            for (int kc = 0; kc < 8; ++kc)
                acc = __builtin_amdgcn_mfma_f32_16x16x32_bf16(Af[kc], Bf[t][kc], acc, 0, 0, 0);
            int col = 64 * w + 16 * t + n;
#pragma unroll
            for (int r = 0; r < 4; ++r) {
                int m = m0 + 4 * q + r;
                h1b[(size_t)m * 288 + col] = bf16_rne(fmaxf(acc[r] + bia[t], 0.f));
            }
        }
    }
}

// ---------------- precompute final projection vectors ----------------
__global__ __launch_bounds__(256) void precompute_kernel(
    const float* __restrict__ ow, const float* __restrict__ llw1,
    const float* __restrict__ lrw1, const float* __restrict__ llb1,
    const float* __restrict__ ob,
    float* __restrict__ v1, float* __restrict__ v2, float* __restrict__ cbuf)
{
    __shared__ float w[256];
    __shared__ float red[256];
    int t = threadIdx.x;
    w[t] = ow[t];
    __syncthreads();
    float s1 = 0.f, s2 = 0.f;
    for (int o = 0; o < 256; ++o) {
        float wo = w[o];
        s1 += wo * llw1[o * 256 + t];
        s2 += wo * lrw1[o * 256 + t];
    }
    v1[t] = s1;
    v2[t] = s2;
    red[t] = w[t] * llb1[t];
    __syncthreads();
    for (int d = 128; d > 0; d >>= 1) {
        if (t < d) red[t] += red[t + d];
        __syncthreads();
    }
    if (t == 0) cbuf[0] = red[0] + ob[0];
}

// ---------------- conv1 aggregation fused with final projection ----------------
__global__ __launch_bounds__(256) void agg1_final_kernel(
    const int* __restrict__ off, const int* __restrict__ eid,
    const int* __restrict__ src, const float* __restrict__ A,
    const ushort* __restrict__ h1b, const float* __restrict__ v1,
    const float* __restrict__ v2, const float* __restrict__ cbuf,
    float* __restrict__ out)
{
    int wave = threadIdx.x >> 6, lane = threadIdx.x & 63;
    int n = blockIdx.x * 4 + wave;
    if (n >= cN2) return;
    int s0 = off[n], s1 = off[n + 1];
    float ax = 0.f, ay = 0.f, az = 0.f, aw = 0.f, accA = 0.f;
    int e = 0, sn = 0; float a = 0.f;
    if (s0 < s1) { e = eid[s0]; a = A[e]; sn = src[e]; }
    for (int idx = s0; idx < s1; ++idx) {
        float ca = a; int cs = sn;
        if (idx + 1 < s1) { int e2 = eid[idx + 1]; a = A[e2]; sn = src[e2]; }
        ushort4 v = *(const ushort4*)&h1b[(size_t)cs * 288 + 4 * lane];
        ax += ca * b2f(v.x); ay += ca * b2f(v.y);
        az += ca * b2f(v.z); aw += ca * b2f(v.w);
        accA += ca;
    }
    float r = (accA > 0.f) ? (1.f / accA) : 0.f;
    ushort4 t4 = *(const ushort4*)&h1b[(size_t)n * 288 + 4 * lane];
    float4 w1v = *(const float4*)&v1[4 * lane];
    float4 w2v = *(const float4*)&v2[4 * lane];
    float p = r * (ax * w1v.x + ay * w1v.y + az * w1v.z + aw * w1v.w)
            + b2f(t4.x) * w2v.x + b2f(t4.y) * w2v.y
            + b2f(t4.z) * w2v.z + b2f(t4.w) * w2v.w;
    p = wave_sum(p);
    if (lane == 0) out[n] = p + cbuf[0];
}

extern "C" void kernel_launch(void* const* d_in, const int* in_sizes, int n_in,
                              void* d_out, int out_size, void* d_ws, size_t ws_size,
                              hipStream_t stream)
{
    const int*   x     = (const int*)d_in[0];
    const float* xu    = (const float*)d_in[1];
    const int*   src0  = (const int*)d_in[2];
    const int*   dst0  = (const int*)d_in[3];
    const int*   src1  = (const int*)d_in[4];
    const int*   dst1  = (const int*)d_in[5];
    const float* emb   = (const float*)d_in[6];
    const float* ln_g  = (const float*)d_in[7];
    const float* ln_b  = (const float*)d_in[8];
    const float* lp_w1 = (const float*)d_in[9];
    const float* lp_b1 = (const float*)d_in[10];
    const float* lp_g  = (const float*)d_in[11];
    const float* lp_bn = (const float*)d_in[12];
    const float* lp_w2 = (const float*)d_in[13];
    const float* lp_b2 = (const float*)d_in[14];
    const float* ll_w0 = (const float*)d_in[15];
    const float* ll_b0 = (const float*)d_in[16];
    const float* lr_w0 = (const float*)d_in[17];
    const float* ll_w1 = (const float*)d_in[18];
    const float* ll_b1 = (const float*)d_in[19];
    const float* lr_w1 = (const float*)d_in[20];
    const float* out_w = (const float*)d_in[21];
    const float* out_b = (const float*)d_in[22];
    float* out = (float*)d_out;

    char* ws = (char*)d_ws;
    size_t off = 0;
    auto alloc = [&](size_t bytes) -> void* {
        void* p = ws + off;
        off = (off + bytes + 255) & ~(size_t)255;
        return p;
    };
    ushort* embB = (ushort*)alloc((size_t)cV * cIN * 2);    // 25.6 MB
    ushort* xub  = (ushort*)alloc((size_t)cN0 * cU * 2);    // 12.8 MB
    ushort* e0   = (ushort*)alloc((size_t)cN0 * cIN * 2);   // 51.2 MB
    ushort* aggn = (ushort*)alloc((size_t)cN1 * cIN * 2);   // 12.8 MB
    ushort* h1b  = (ushort*)alloc((size_t)cN1 * 288 * 2);   // 28.8 MB
    float* A0    = (float*)alloc((size_t)cE0 * 4);
    float* A1    = (float*)alloc((size_t)cE1 * 4);
    ushort* Wb   = (ushort*)alloc((size_t)256 * 256 * 2);
    float* v1    = (float*)alloc(256 * 4);
    float* v2    = (float*)alloc(256 * 4);
    float* cbuf  = (float*)alloc(64);
    int* cnt0    = (int*)alloc((size_t)cN1 * 4);
    int* off0    = (int*)alloc((size_t)(cN1 + 1) * 4);
    int* pos0    = (int*)alloc((size_t)cN1 * 4);
    int* eid0    = (int*)alloc((size_t)cE0 * 4);
    int* cnt1    = (int*)alloc((size_t)cN2 * 4);
    int* off1    = (int*)alloc((size_t)(cN2 + 1) * 4);
    int* pos1    = (int*)alloc((size_t)cN2 * 4);
    int* eid1    = (int*)alloc((size_t)cE1 * 4);

    hipMemsetAsync(cnt0, 0, (size_t)cN1 * 4, stream);
    hipMemsetAsync(pos0, 0, (size_t)cN1 * 4, stream);
    hipMemsetAsync(cnt1, 0, (size_t)cN2 * 4, stream);
    hipMemsetAsync(pos1, 0, (size_t)cN2 * 4, stream);

    cvt4_kernel<<<(cV * cIN) / 1024, 256, 0, stream>>>(emb, embB);
    cvt4_kernel<<<(cN0 * cU) / 1024, 256, 0, stream>>>(xu, xub);
    cvt_w0_kernel<<<128, 256, 0, stream>>>(ll_w0, lr_w0, Wb);

    embed_kernel<<<cN0 / 4, 256, 0, stream>>>(x, embB, ln_g, ln_b, e0);

    count_kernel<<<(cE0 + 255) / 256, 256, 0, stream>>>(dst0, cE0, cnt0);
    scan_kernel<<<1, 1024, 0, stream>>>(cnt0, off0, cN1);
    scatter_kernel<<<(cE0 + 255) / 256, 256, 0, stream>>>(dst0, cE0, off0, pos0, eid0);

    edge_mlp_mfma_kernel<<<1024, 256, 0, stream>>>(xub, cU, xub, cU, src0, dst0, cE0,
                                                   lp_w1, lp_b1, lp_g, lp_bn, lp_w2, lp_b2, A0);

    agg0_kernel<<<(cN1 + 3) / 4, 256, 0, stream>>>(off0, eid0, src0, A0, e0, xub, aggn, h1b);

    linear0_mfma_kernel<<<784, 256, 0, stream>>>(aggn, e0, Wb, ll_b0, h1b);

    count_kernel<<<(cE1 + 255) / 256, 256, 0, stream>>>(dst1, cE1, cnt1);
    scan_kernel<<<1, 1024, 0, stream>>>(cnt1, off1, cN2);
    scatter_kernel<<<(cE1 + 255) / 256, 256, 0, stream>>>(dst1, cE1, off1, pos1, eid1);

    edge_mlp_mfma_kernel<<<512, 256, 0, stream>>>(h1b + 256, 288, h1b + 256, 288, src1, dst1, cE1,
                                                  lp_w1, lp_b1, lp_g, lp_bn, lp_w2, lp_b2, A1);

    precompute_kernel<<<1, 256, 0, stream>>>(out_w, ll_w1, lr_w1, ll_b1, out_b, v1, v2, cbuf);

    agg1_final_kernel<<<(cN2 + 3) / 4, 256, 0, stream>>>(off1, eid1, src1, A1, h1b, v1, v2, cbuf, out);
}

// Round 5
// 690.519 us; speedup vs baseline: 2.5602x; 1.1134x over previous
//
#include <hip/hip_runtime.h>
#include <math.h>

#define cN0 200000
#define cN1 50000
#define cN2 10000
#define cL  10
#define cE0 800000
#define cE1 160000
#define cV  100000
#define cIN 128
#define cH  256
#define cU  32
#define cLP 128

typedef __attribute__((ext_vector_type(8))) short short8;
typedef __attribute__((ext_vector_type(4))) float floatx4;

__device__ __forceinline__ float wave_sum(float v) {
#pragma unroll
    for (int m = 1; m < 64; m <<= 1) v += __shfl_xor(v, m);
    return v;
}

__device__ __forceinline__ float red16(float v) {
    v += __shfl_xor(v, 1); v += __shfl_xor(v, 2);
    v += __shfl_xor(v, 4); v += __shfl_xor(v, 8);
    return v;
}

__device__ __forceinline__ unsigned short bf16_rne(float f) {
    union { float f; unsigned u; } c; c.f = f;
    unsigned r = (c.u + 0x7FFFu + ((c.u >> 16) & 1u)) >> 16;
    return (unsigned short)r;
}

__device__ __forceinline__ float b2f(unsigned short u) {
    union { unsigned u; float f; } c; c.u = ((unsigned)u) << 16;
    return c.f;
}

// ---------------- fp32 -> bf16 converters ----------------
__global__ __launch_bounds__(256) void cvt4_kernel(const float* __restrict__ src,
                                                   ushort* __restrict__ dstp)
{
    size_t i = ((size_t)blockIdx.x * 256 + threadIdx.x) * 4;
    float4 v = *(const float4*)&src[i];
    ushort4 o;
    o.x = bf16_rne(v.x); o.y = bf16_rne(v.y);
    o.z = bf16_rne(v.z); o.w = bf16_rne(v.w);
    *(ushort4*)&dstp[i] = o;
}

// ---------------- build Wb[o][k] bf16 (k<128 -> ll_w0, else lr_w0) ----------------
__global__ __launch_bounds__(256) void cvt_w0_kernel(const float* __restrict__ llw0,
                                                     const float* __restrict__ lrw0,
                                                     ushort* __restrict__ Wb)
{
    int idx = blockIdx.x * 256 + threadIdx.x;
    int i = idx * 2;
    int o = i >> 8, k = i & 255;
    float2 v = (k < 128) ? *(const float2*)&llw0[o * 128 + k]
                         : *(const float2*)&lrw0[o * 128 + (k - 128)];
    ushort2 w;
    w.x = bf16_rne(v.x); w.y = bf16_rne(v.y);
    *(ushort2*)&Wb[i] = w;
}

// ---------------- embedding + LN + relu -> e0 bf16 (branchless, 10-deep ILP) --------
__global__ __launch_bounds__(256) void embed_kernel(
    const int* __restrict__ x, const ushort* __restrict__ embB,
    const float* __restrict__ g, const float* __restrict__ b,
    ushort* __restrict__ e0)
{
    int wave = threadIdx.x >> 6, lane = threadIdx.x & 63;
    int n = blockIdx.x * 4 + wave;
    const int* xr = x + (size_t)n * cL;
    int toks[cL];
#pragma unroll
    for (int t = 0; t < cL; ++t) toks[t] = xr[t];
    unsigned packed[cL];
#pragma unroll
    for (int t = 0; t < cL; ++t)
        packed[t] = *(const unsigned*)&embB[(size_t)toks[t] * cIN + 2 * lane];
    float ax = 0.f, ay = 0.f;
#pragma unroll
    for (int t = 0; t < cL; ++t) {
        unsigned p = (toks[t] != 0) ? packed[t] : 0u;
        union { unsigned u; float f; } lo, hi;
        lo.u = p << 16; hi.u = p & 0xFFFF0000u;
        ax += lo.f; ay += hi.f;
    }
    float s1 = wave_sum(ax + ay);
    float s2 = wave_sum(ax * ax + ay * ay);
    float mean = s1 * (1.f / cIN);
    float var = s2 * (1.f / cIN) - mean * mean;
    float rstd = rsqrtf(var + 1e-5f);
    float2 gv = *(const float2*)&g[2 * lane];
    float2 bv = *(const float2*)&b[2 * lane];
    ushort2 o;
    o.x = bf16_rne(fmaxf((ax - mean) * rstd * gv.x + bv.x, 0.f));
    o.y = bf16_rne(fmaxf((ay - mean) * rstd * gv.y + bv.y, 0.f));
    *(ushort2*)&e0[(size_t)n * cIN + 2 * lane] = o;
}

// ---------------- CSR build ----------------
__global__ void count_kernel(const int* __restrict__ dst, int E, int* __restrict__ cnt)
{
    int e = blockIdx.x * 256 + threadIdx.x;
    if (e < E) atomicAdd(&cnt[dst[e]], 1);
}

__global__ __launch_bounds__(1024) void scan_kernel(const int* __restrict__ cnt,
                                                    int* __restrict__ off, int n)
{
    __shared__ int ps[1024];
    int t = threadIdx.x;
    int chunk = (n + 1023) / 1024;
    int lo = t * chunk;
    int hi = min(lo + chunk, n);
    int s = 0;
    for (int i = lo; i < hi; ++i) s += cnt[i];
    ps[t] = s;
    __syncthreads();
    for (int d = 1; d < 1024; d <<= 1) {
        int v = (t >= d) ? ps[t - d] : 0;
        __syncthreads();
        ps[t] += v;
        __syncthreads();
    }
    int run = ps[t] - s;
    for (int i = lo; i < hi; ++i) { off[i] = run; run += cnt[i]; }
    if (hi == n) off[n] = run;
}

__global__ void scatter_kernel(const int* __restrict__ dst, int E,
                               const int* __restrict__ off, int* __restrict__ pos,
                               int* __restrict__ eid)
{
    int e = blockIdx.x * 256 + threadIdx.x;
    if (e < E) {
        int d = dst[e];
        int p = atomicAdd(&pos[d], 1);
        eid[off[d] + p] = e;
    }
}

// ---------------- edge MLP via MFMA bf16 (u tables in bf16) ----------------
__global__ __launch_bounds__(256) void edge_mlp_mfma_kernel(
    const ushort* __restrict__ uni, int stride_i,
    const ushort* __restrict__ unj, int stride_j,
    const int* __restrict__ src, const int* __restrict__ dst, int E,
    const float* __restrict__ w1, const float* __restrict__ b1v,
    const float* __restrict__ gv, const float* __restrict__ bnv,
    const float* __restrict__ w2, const float* __restrict__ b2,
    float* __restrict__ A)
{
    __shared__ float par[cLP * 4];  // o -> (b1, g, bn, w2)
    int tid = threadIdx.x;
    if (tid < cLP) {
        par[tid * 4 + 0] = b1v[tid];
        par[tid * 4 + 1] = gv[tid];
        par[tid * 4 + 2] = bnv[tid];
        par[tid * 4 + 3] = w2[tid];
    }
    int lane = tid & 63;
    int n = lane & 15, q = lane >> 4;

    short8 Bf[8][3];
#pragma unroll
    for (int nt = 0; nt < 8; ++nt) {
#pragma unroll
        for (int c = 0; c < 3; ++c) {
            const float* p = &w1[(size_t)(16 * nt + n) * 96 + 32 * c + 8 * q];
            float4 v0 = *(const float4*)p;
            float4 v1 = *(const float4*)(p + 4);
            short8 s;
            s[0] = bf16_rne(v0.x); s[1] = bf16_rne(v0.y);
            s[2] = bf16_rne(v0.z); s[3] = bf16_rne(v0.w);
            s[4] = bf16_rne(v1.x); s[5] = bf16_rne(v1.y);
            s[6] = bf16_rne(v1.z); s[7] = bf16_rne(v1.w);
            Bf[nt][c] = s;
        }
    }
    __syncthreads();
    float b2s = b2[0];

    int wid = blockIdx.x * 4 + (tid >> 6);
    int nw = gridDim.x * 4;
    int ngroups = E >> 4;

    int g = wid;
    int di = 0, si = 0;
    if (g < ngroups) {
        int e = (g << 4) + n;
        di = dst[e]; si = src[e];
    }
    while (g < ngroups) {
        short8 iv = *(const short8*)&uni[(size_t)di * stride_i + 8 * q];
        short8 jv = *(const short8*)&unj[(size_t)si * stride_j + 8 * q];
        int gn = g + nw;
        if (gn < ngroups) {
            int e2 = (gn << 4) + n;
            di = dst[e2]; si = src[e2];
        }
        short8 a0, a1, a2;
#pragma unroll
        for (int j = 0; j < 8; ++j) {
            float u = b2f((unsigned short)iv[j]);
            float v = b2f((unsigned short)jv[j]);
            a0[j] = bf16_rne(fabsf(u - v));
            a1[j] = bf16_rne(u + v);
            a2[j] = bf16_rne(u * v);
        }
        floatx4 acc[8];
#pragma unroll
        for (int nt = 0; nt < 8; ++nt) acc[nt] = (floatx4){0.f, 0.f, 0.f, 0.f};
#pragma unroll
        for (int nt = 0; nt < 8; ++nt) {
            acc[nt] = __builtin_amdgcn_mfma_f32_16x16x32_bf16(a0, Bf[nt][0], acc[nt], 0, 0, 0);
            acc[nt] = __builtin_amdgcn_mfma_f32_16x16x32_bf16(a1, Bf[nt][1], acc[nt], 0, 0, 0);
            acc[nt] = __builtin_amdgcn_mfma_f32_16x16x32_bf16(a2, Bf[nt][2], acc[nt], 0, 0, 0);
        }
        float s1[4] = {0.f, 0.f, 0.f, 0.f}, s2[4] = {0.f, 0.f, 0.f, 0.f};
#pragma unroll
        for (int nt = 0; nt < 8; ++nt) {
            float4 pp = *(const float4*)&par[(16 * nt + n) * 4];
#pragma unroll
            for (int r = 0; r < 4; ++r) {
                float h = acc[nt][r] + pp.x;
                acc[nt][r] = h;
                s1[r] += h; s2[r] += h * h;
            }
        }
        float mean[4], rstd[4];
#pragma unroll
        for (int r = 0; r < 4; ++r) {
            s1[r] = red16(s1[r]); s2[r] = red16(s2[r]);
            mean[r] = s1[r] * (1.f / 128.f);
            float var = s2[r] * (1.f / 128.f) - mean[r] * mean[r];
            rstd[r] = rsqrtf(var + 1e-5f);
        }
        float p[4] = {0.f, 0.f, 0.f, 0.f};
#pragma unroll
        for (int nt = 0; nt < 8; ++nt) {
            float4 pp = *(const float4*)&par[(16 * nt + n) * 4];
#pragma unroll
            for (int r = 0; r < 4; ++r) {
                float y = fmaxf((acc[nt][r] - mean[r]) * rstd[r] * pp.y + pp.z, 0.f);
                p[r] += y * pp.w;
            }
        }
#pragma unroll
        for (int r = 0; r < 4; ++r) p[r] = red16(p[r]);
        if (n < 4) {
            float pv = p[n];
            A[(g << 4) + 4 * q + n] = 1.f / (1.f + expf(-(pv + b2s)));
        }
        g = gn;
    }
}

// ---------------- conv0 aggregation: 4-deep MLP unrolled gather ----------------
// lanes 0..31: feat (e0 rows, 4 ch/lane), lanes 32..39: un (xub rows, 4 ch/lane);
// lanes 40..63 duplicate 32..39 (loads wasted, writes masked).
__global__ __launch_bounds__(256) void agg0_kernel(
    const int* __restrict__ off, const int* __restrict__ eid,
    const int* __restrict__ src, const float* __restrict__ A,
    const ushort* __restrict__ e0, const ushort* __restrict__ xub,
    ushort* __restrict__ aggn, ushort* __restrict__ h1b)
{
    int wave = threadIdx.x >> 6, lane = threadIdx.x & 63;
    int i = blockIdx.x * 4 + wave;
    if (i >= cN1) return;
    int s0 = off[i], s1 = off[i + 1];
    bool feat = lane < 32;
    int col = feat ? (4 * lane) : (4 * (lane & 7));
    const ushort* base = feat ? e0 : xub;
    int stride = feat ? cIN : cU;
    float ax = 0.f, ay = 0.f, az = 0.f, aw = 0.f, accA = 0.f;
    int idx = s0;
    for (; idx + 4 <= s1; idx += 4) {
        int ea = eid[idx], eb = eid[idx + 1], ec = eid[idx + 2], ed = eid[idx + 3];
        float aa = A[ea], ab = A[eb], ac = A[ec], ad = A[ed];
        int sa = src[ea], sb = src[eb], sc = src[ec], sd = src[ed];
        ushort4 va = *(const ushort4*)&base[(size_t)sa * stride + col];
        ushort4 vb = *(const ushort4*)&base[(size_t)sb * stride + col];
        ushort4 vc = *(const ushort4*)&base[(size_t)sc * stride + col];
        ushort4 vd = *(const ushort4*)&base[(size_t)sd * stride + col];
        float wa = feat ? aa : 1.f, wb = feat ? ab : 1.f;
        float wc = feat ? ac : 1.f, wd = feat ? ad : 1.f;
        ax += wa * b2f(va.x) + wb * b2f(vb.x) + wc * b2f(vc.x) + wd * b2f(vd.x);
        ay += wa * b2f(va.y) + wb * b2f(vb.y) + wc * b2f(vc.y) + wd * b2f(vd.y);
        az += wa * b2f(va.z) + wb * b2f(vb.z) + wc * b2f(vc.z) + wd * b2f(vd.z);
        aw += wa * b2f(va.w) + wb * b2f(vb.w) + wc * b2f(vc.w) + wd * b2f(vd.w);
        accA += aa + ab + ac + ad;
    }
    for (; idx < s1; ++idx) {
        int e = eid[idx];
        float a = A[e];
        int s = src[e];
        ushort4 v = *(const ushort4*)&base[(size_t)s * stride + col];
        float w = feat ? a : 1.f;
        ax += w * b2f(v.x); ay += w * b2f(v.y);
        az += w * b2f(v.z); aw += w * b2f(v.w);
        accA += a;
    }
    if (feat) {
        float r = (accA > 0.f) ? (1.f / accA) : 0.f;
        ushort4 o;
        o.x = bf16_rne(ax * r); o.y = bf16_rne(ay * r);
        o.z = bf16_rne(az * r); o.w = bf16_rne(aw * r);
        *(ushort4*)&aggn[(size_t)i * cIN + col] = o;
    } else if (lane < 40) {
        ushort4 o;
        o.x = bf16_rne(ax); o.y = bf16_rne(ay);
        o.z = bf16_rne(az); o.w = bf16_rne(aw);
        *(ushort4*)&h1b[(size_t)i * 288 + 256 + col] = o;
    }
}

// ---------------- linear0 via MFMA: h1b[:, :256] = relu([aggn|e0] @ Wb.T + b) --------
__global__ __launch_bounds__(256) void linear0_mfma_kernel(
    const ushort* __restrict__ aggn, const ushort* __restrict__ e0,
    const ushort* __restrict__ Wb, const float* __restrict__ bias,
    ushort* __restrict__ h1b)
{
    int tid = threadIdx.x;
    int w = tid >> 6, lane = tid & 63;
    int n = lane & 15, q = lane >> 4;
    short8 Bf[4][8];
    float bia[4];
#pragma unroll
    for (int t = 0; t < 4; ++t) {
        int col = 64 * w + 16 * t + n;
        bia[t] = bias[col];
#pragma unroll
        for (int kc = 0; kc < 8; ++kc)
            Bf[t][kc] = *(const short8*)&Wb[(size_t)col * 256 + kc * 32 + 8 * q];
    }
    for (int g = blockIdx.x; g < cN1 / 16; g += gridDim.x) {
        int m0 = g * 16;
        int row = m0 + n;
        short8 Af[8];
#pragma unroll
        for (int kc = 0; kc < 4; ++kc)
            Af[kc] = *(const short8*)&aggn[(size_t)row * cIN + kc * 32 + 8 * q];
#pragma unroll
        for (int kc = 0; kc < 4; ++kc)
            Af[4 + kc] = *(const short8*)&e0[(size_t)row * cIN + kc * 32 + 8 * q];
#pragma unroll
        for (int t = 0; t < 4; ++t) {
            floatx4 acc = {0.f, 0.f, 0.f, 0.f};
#pragma unroll
            for (int kc = 0; kc < 8; ++kc)
                acc = __builtin_amdgcn_mfma_f32_16x16x32_bf16(Af[kc], Bf[t][kc], acc, 0, 0, 0);
            int col = 64 * w + 16 * t + n;
#pragma unroll
            for (int r = 0; r < 4; ++r) {
                int m = m0 + 4 * q + r;
                h1b[(size_t)m * 288 + col] = bf16_rne(fmaxf(acc[r] + bia[t], 0.f));
            }
        }
    }
}

// ---------------- precompute final projection vectors ----------------
__global__ __launch_bounds__(256) void precompute_kernel(
    const float* __restrict__ ow, const float* __restrict__ llw1,
    const float* __restrict__ lrw1, const float* __restrict__ llb1,
    const float* __restrict__ ob,
    float* __restrict__ v1, float* __restrict__ v2, float* __restrict__ cbuf)
{
    __shared__ float w[256];
    __shared__ float red[256];
    int t = threadIdx.x;
    w[t] = ow[t];
    __syncthreads();
    float s1 = 0.f, s2 = 0.f;
    for (int o = 0; o < 256; ++o) {
        float wo = w[o];
        s1 += wo * llw1[o * 256 + t];
        s2 += wo * lrw1[o * 256 + t];
    }
    v1[t] = s1;
    v2[t] = s2;
    red[t] = w[t] * llb1[t];
    __syncthreads();
    for (int d = 128; d > 0; d >>= 1) {
        if (t < d) red[t] += red[t + d];
        __syncthreads();
    }
    if (t == 0) cbuf[0] = red[0] + ob[0];
}

// ---------------- conv1 aggregation fused with final projection (4-deep MLP) --------
__global__ __launch_bounds__(256) void agg1_final_kernel(
    const int* __restrict__ off, const int* __restrict__ eid,
    const int* __restrict__ src, const float* __restrict__ A,
    const ushort* __restrict__ h1b, const float* __restrict__ v1,
    const float* __restrict__ v2, const float* __restrict__ cbuf,
    float* __restrict__ out)
{
    int wave = threadIdx.x >> 6, lane = threadIdx.x & 63;
    int n = blockIdx.x * 4 + wave;
    if (n >= cN2) return;
    int s0 = off[n], s1 = off[n + 1];
    float ax = 0.f, ay = 0.f, az = 0.f, aw = 0.f, accA = 0.f;
    int idx = s0;
    for (; idx + 4 <= s1; idx += 4) {
        int ea = eid[idx], eb = eid[idx + 1], ec = eid[idx + 2], ed = eid[idx + 3];
        float aa = A[ea], ab = A[eb], ac = A[ec], ad = A[ed];
        int sa = src[ea], sb = src[eb], sc = src[ec], sd = src[ed];
        ushort4 va = *(const ushort4*)&h1b[(size_t)sa * 288 + 4 * lane];
        ushort4 vb = *(const ushort4*)&h1b[(size_t)sb * 288 + 4 * lane];
        ushort4 vc = *(const ushort4*)&h1b[(size_t)sc * 288 + 4 * lane];
        ushort4 vd = *(const ushort4*)&h1b[(size_t)sd * 288 + 4 * lane];
        ax += aa * b2f(va.x) + ab * b2f(vb.x) + ac * b2f(vc.x) + ad * b2f(vd.x);
        ay += aa * b2f(va.y) + ab * b2f(vb.y) + ac * b2f(vc.y) + ad * b2f(vd.y);
        az += aa * b2f(va.z) + ab * b2f(vb.z) + ac * b2f(vc.z) + ad * b2f(vd.z);
        aw += aa * b2f(va.w) + ab * b2f(vb.w) + ac * b2f(vc.w) + ad * b2f(vd.w);
        accA += aa + ab + ac + ad;
    }
    for (; idx < s1; ++idx) {
        int e = eid[idx];
        float a = A[e];
        int s = src[e];
        ushort4 v = *(const ushort4*)&h1b[(size_t)s * 288 + 4 * lane];
        ax += a * b2f(v.x); ay += a * b2f(v.y);
        az += a * b2f(v.z); aw += a * b2f(v.w);
        accA += a;
    }
    float r = (accA > 0.f) ? (1.f / accA) : 0.f;
    ushort4 t4 = *(const ushort4*)&h1b[(size_t)n * 288 + 4 * lane];
    float4 w1v = *(const float4*)&v1[4 * lane];
    float4 w2v = *(const float4*)&v2[4 * lane];
    float p = r * (ax * w1v.x + ay * w1v.y + az * w1v.z + aw * w1v.w)
            + b2f(t4.x) * w2v.x + b2f(t4.y) * w2v.y
            + b2f(t4.z) * w2v.z + b2f(t4.w) * w2v.w;
    p = wave_sum(p);
    if (lane == 0) out[n] = p + cbuf[0];
}

extern "C" void kernel_launch(void* const* d_in, const int* in_sizes, int n_in,
                              void* d_out, int out_size, void* d_ws, size_t ws_size,
                              hipStream_t stream)
{
    const int*   x     = (const int*)d_in[0];
    const float* xu    = (const float*)d_in[1];
    const int*   src0  = (const int*)d_in[2];
    const int*   dst0  = (const int*)d_in[3];
    const int*   src1  = (const int*)d_in[4];
    const int*   dst1  = (const int*)d_in[5];
    const float* emb   = (const float*)d_in[6];
    const float* ln_g  = (const float*)d_in[7];
    const float* ln_b  = (const float*)d_in[8];
    const float* lp_w1 = (const float*)d_in[9];
    const float* lp_b1 = (const float*)d_in[10];
    const float* lp_g  = (const float*)d_in[11];
    const float* lp_bn = (const float*)d_in[12];
    const float* lp_w2 = (const float*)d_in[13];
    const float* lp_b2 = (const float*)d_in[14];
    const float* ll_w0 = (const float*)d_in[15];
    const float* ll_b0 = (const float*)d_in[16];
    const float* lr_w0 = (const float*)d_in[17];
    const float* ll_w1 = (const float*)d_in[18];
    const float* ll_b1 = (const float*)d_in[19];
    const float* lr_w1 = (const float*)d_in[20];
    const float* out_w = (const float*)d_in[21];
    const float* out_b = (const float*)d_in[22];
    float* out = (float*)d_out;

    char* ws = (char*)d_ws;
    size_t off = 0;
    auto alloc = [&](size_t bytes) -> void* {
        void* p = ws + off;
        off = (off + bytes + 255) & ~(size_t)255;
        return p;
    };
    ushort* embB = (ushort*)alloc((size_t)cV * cIN * 2);
    ushort* xub  = (ushort*)alloc((size_t)cN0 * cU * 2);
    ushort* e0   = (ushort*)alloc((size_t)cN0 * cIN * 2);
    ushort* aggn = (ushort*)alloc((size_t)cN1 * cIN * 2);
    ushort* h1b  = (ushort*)alloc((size_t)cN1 * 288 * 2);
    float* A0    = (float*)alloc((size_t)cE0 * 4);
    float* A1    = (float*)alloc((size_t)cE1 * 4);
    ushort* Wb   = (ushort*)alloc((size_t)256 * 256 * 2);
    float* v1    = (float*)alloc(256 * 4);
    float* v2    = (float*)alloc(256 * 4);
    float* cbuf  = (float*)alloc(64);
    int* cnt0    = (int*)alloc((size_t)cN1 * 4);
    int* off0    = (int*)alloc((size_t)(cN1 + 1) * 4);
    int* pos0    = (int*)alloc((size_t)cN1 * 4);
    int* eid0    = (int*)alloc((size_t)cE0 * 4);
    int* cnt1    = (int*)alloc((size_t)cN2 * 4);
    int* off1    = (int*)alloc((size_t)(cN2 + 1) * 4);
    int* pos1    = (int*)alloc((size_t)cN2 * 4);
    int* eid1    = (int*)alloc((size_t)cE1 * 4);

    hipMemsetAsync(cnt0, 0, (size_t)cN1 * 4, stream);
    hipMemsetAsync(pos0, 0, (size_t)cN1 * 4, stream);
    hipMemsetAsync(cnt1, 0, (size_t)cN2 * 4, stream);
    hipMemsetAsync(pos1, 0, (size_t)cN2 * 4, stream);

    cvt4_kernel<<<(cV * cIN) / 1024, 256, 0, stream>>>(emb, embB);
    cvt4_kernel<<<(cN0 * cU) / 1024, 256, 0, stream>>>(xu, xub);
    cvt_w0_kernel<<<128, 256, 0, stream>>>(ll_w0, lr_w0, Wb);

    embed_kernel<<<cN0 / 4, 256, 0, stream>>>(x, embB, ln_g, ln_b, e0);

    count_kernel<<<(cE0 + 255) / 256, 256, 0, stream>>>(dst0, cE0, cnt0);
    scan_kernel<<<1, 1024, 0, stream>>>(cnt0, off0, cN1);
    scatter_kernel<<<(cE0 + 255) / 256, 256, 0, stream>>>(dst0, cE0, off0, pos0, eid0);

    edge_mlp_mfma_kernel<<<1024, 256, 0, stream>>>(xub, cU, xub, cU, src0, dst0, cE0,
                                                   lp_w1, lp_b1, lp_g, lp_bn, lp_w2, lp_b2, A0);

    agg0_kernel<<<(cN1 + 3) / 4, 256, 0, stream>>>(off0, eid0, src0, A0, e0, xub, aggn, h1b);

    linear0_mfma_kernel<<<784, 256, 0, stream>>>(aggn, e0, Wb, ll_b0, h1b);

    count_kernel<<<(cE1 + 255) / 256, 256, 0, stream>>>(dst1, cE1, cnt1);
    scan_kernel<<<1, 1024, 0, stream>>>(cnt1, off1, cN2);
    scatter_kernel<<<(cE1 + 255) / 256, 256, 0, stream>>>(dst1, cE1, off1, pos1, eid1);

    edge_mlp_mfma_kernel<<<512, 256, 0, stream>>>(h1b + 256, 288, h1b + 256, 288, src1, dst1, cE1,
                                                  lp_w1, lp_b1, lp_g, lp_bn, lp_w2, lp_b2, A1);

    precompute_kernel<<<1, 256, 0, stream>>>(out_w, ll_w1, lr_w1, ll_b1, out_b, v1, v2, cbuf);

    agg1_final_kernel<<<(cN2 + 3) / 4, 256, 0, stream>>>(off1, eid1, src1, A1, h1b, v1, v2, cbuf, out);
}